// Round 2
// baseline (1734.317 us; speedup 1.0000x reference)
//
#include <hip/hip_runtime.h>
#include <cstddef>

#define NN 20000
#define EE 100000
#define NR 6
#define HH 2
#define NEG 0.2f

struct EdgePtrs { const int* e[NR]; };

__device__ __forceinline__ unsigned f2o(float f) {
    unsigned u = __float_as_uint(f);
    return (u & 0x80000000u) ? ~u : (u | 0x80000000u);
}
__device__ __forceinline__ float o2f(unsigned u) {
    return (u & 0x80000000u) ? __uint_as_float(u & 0x7fffffffu) : __uint_as_float(~u);
}

// w~[h][k] = sum_c a[h,c] * W[h*C+c, k]
__global__ void fold_a_kernel(const float* __restrict__ W, const float* __restrict__ a,
                              float* __restrict__ wt, int C, int K) {
    int k = blockIdx.x * 256 + threadIdx.x;
    int h = blockIdx.y;
    if (k >= K) return;
    float acc = 0.f;
    for (int c = 0; c < C; ++c)
        acc = fmaf(a[h * C + c], W[(size_t)(h * C + c) * K + k], acc);
    wt[h * K + k] = acc;
}

// C[M,Nn] = A[M,K] @ B[Nn,K]^T   (fp32, 64x64x16 tile, 256 thr, 4x4/thread)
__global__ void gemm_nt(const float* __restrict__ A, const float* __restrict__ B,
                        float* __restrict__ C, int M, int Nn, int K) {
    __shared__ float As[16][68];
    __shared__ float Bs[16][68];
    int tid = threadIdx.x;
    int tm = (tid / 16) * 4;
    int tn = (tid % 16) * 4;
    int row0 = blockIdx.y * 64, col0 = blockIdx.x * 64;
    int lr = tid / 4;
    int lk4 = (tid % 4) * 4;
    float acc[4][4] = {};
    for (int k0 = 0; k0 < K; k0 += 16) {
        float4 av = make_float4(0.f, 0.f, 0.f, 0.f);
        int ar = row0 + lr;
        if (ar < M) av = *(const float4*)&A[(size_t)ar * K + k0 + lk4];
        As[lk4 + 0][lr] = av.x; As[lk4 + 1][lr] = av.y;
        As[lk4 + 2][lr] = av.z; As[lk4 + 3][lr] = av.w;
        float4 bv = *(const float4*)&B[(size_t)(col0 + lr) * K + k0 + lk4];
        Bs[lk4 + 0][lr] = bv.x; Bs[lk4 + 1][lr] = bv.y;
        Bs[lk4 + 2][lr] = bv.z; Bs[lk4 + 3][lr] = bv.w;
        __syncthreads();
#pragma unroll
        for (int k = 0; k < 16; ++k) {
            float a_[4], b_[4];
#pragma unroll
            for (int i = 0; i < 4; ++i) a_[i] = As[k][tm + i];
#pragma unroll
            for (int j = 0; j < 4; ++j) b_[j] = Bs[k][tn + j];
#pragma unroll
            for (int i = 0; i < 4; ++i)
#pragma unroll
                for (int j = 0; j < 4; ++j) acc[i][j] = fmaf(a_[i], b_[j], acc[i][j]);
        }
        __syncthreads();
    }
    for (int i = 0; i < 4; ++i) {
        int r = row0 + tm + i;
        if (r < M) {
            for (int j = 0; j < 4; ++j)
                C[(size_t)r * Nn + col0 + tn + j] = acc[i][j];
        }
    }
}

// per node: al_src/al_dst (x . w~), l_self, init m for all relations, zero count
__global__ void al_kernel(const float* __restrict__ x, const float* __restrict__ wts,
                          const float* __restrict__ wtd, int K,
                          float* __restrict__ al_src, float* __restrict__ al_dst,
                          float* __restrict__ lself, unsigned* __restrict__ m,
                          int* __restrict__ count) {
    int n = blockIdx.x;
    int tid = threadIdx.x;
    __shared__ float red[4][256];
    float p0 = 0.f, p1 = 0.f, p2 = 0.f, p3 = 0.f;
    for (int k = tid; k < K; k += 256) {
        float xv = x[(size_t)n * K + k];
        p0 = fmaf(xv, wts[k], p0);
        p1 = fmaf(xv, wts[K + k], p1);
        p2 = fmaf(xv, wtd[k], p2);
        p3 = fmaf(xv, wtd[K + k], p3);
    }
    red[0][tid] = p0; red[1][tid] = p1; red[2][tid] = p2; red[3][tid] = p3;
    __syncthreads();
    for (int st = 128; st > 0; st >>= 1) {
        if (tid < st) {
            for (int q = 0; q < 4; ++q) red[q][tid] += red[q][tid + st];
        }
        __syncthreads();
    }
    if (tid == 0) {
        for (int h = 0; h < HH; ++h) {
            float as_ = red[h][0], ad_ = red[2 + h][0];
            al_src[n * HH + h] = as_;
            al_dst[n * HH + h] = ad_;
            float l = as_ + ad_;
            l = l > 0.f ? l : NEG * l;
            lself[n * HH + h] = l;
            unsigned enc = f2o(l);
            for (int r = 0; r < NR; ++r) m[(r * NN + n) * HH + h] = enc;
        }
        count[n] = 0;
    }
}

__global__ void edge_logit_max(EdgePtrs ep, const float* __restrict__ al_src,
                               const float* __restrict__ al_dst,
                               float* __restrict__ pbuf, unsigned* __restrict__ m,
                               int* __restrict__ count) {
    int i = blockIdx.x * 256 + threadIdx.x;
    if (i >= NR * EE) return;
    int r = i / EE, ei = i - r * EE;
    const int* e = ep.e[r];
    int sN = e[ei];
    int d = e[EE + ei];
    float l0 = al_src[sN * 2 + 0] + al_dst[d * 2 + 0]; l0 = l0 > 0.f ? l0 : NEG * l0;
    float l1 = al_src[sN * 2 + 1] + al_dst[d * 2 + 1]; l1 = l1 > 0.f ? l1 : NEG * l1;
    pbuf[(size_t)i * 2 + 0] = l0;
    pbuf[(size_t)i * 2 + 1] = l1;
    atomicMax(&m[(r * NN + d) * 2 + 0], f2o(l0));
    atomicMax(&m[(r * NN + d) * 2 + 1], f2o(l1));
    atomicAdd(&count[d], 1);
}

__global__ void s_init_kernel(const float* __restrict__ lself, const unsigned* __restrict__ m,
                              float* __restrict__ s) {
    int i = blockIdx.x * 256 + threadIdx.x;
    if (i >= NR * NN * HH) return;
    int nh = i % (NN * HH);
    s[i] = expf(lself[nh] - o2f(m[i]));
}

__global__ void edge_p_sum(EdgePtrs ep, const unsigned* __restrict__ m,
                           float* __restrict__ pbuf, float* __restrict__ s) {
    int i = blockIdx.x * 256 + threadIdx.x;
    if (i >= NR * EE) return;
    int r = i / EE, ei = i - r * EE;
    int d = ep.e[r][EE + ei];
    float p0 = expf(pbuf[(size_t)i * 2 + 0] - o2f(m[(r * NN + d) * 2 + 0]));
    float p1 = expf(pbuf[(size_t)i * 2 + 1] - o2f(m[(r * NN + d) * 2 + 1]));
    pbuf[(size_t)i * 2 + 0] = p0;
    pbuf[(size_t)i * 2 + 1] = p1;
    atomicAdd(&s[(r * NN + d) * 2 + 0], p0);
    atomicAdd(&s[(r * NN + d) * 2 + 1], p1);
}

__global__ void scan_kernel(const int* __restrict__ count, int* __restrict__ offs,
                            int* __restrict__ cursor) {
    __shared__ int sh[1024];
    __shared__ int carry;
    int tid = threadIdx.x;
    if (tid == 0) carry = 0;
    __syncthreads();
    for (int base = 0; base < NN; base += 1024) {
        int v = (base + tid < NN) ? count[base + tid] : 0;
        sh[tid] = v;
        __syncthreads();
        for (int st = 1; st < 1024; st <<= 1) {
            int t = (tid >= st) ? sh[tid - st] : 0;
            __syncthreads();
            sh[tid] += t;
            __syncthreads();
        }
        int excl = sh[tid] - v + carry;
        if (base + tid < NN) { offs[base + tid] = excl; cursor[base + tid] = excl; }
        __syncthreads();
        if (tid == 0) carry += sh[1023];
        __syncthreads();
    }
    if (tid == 0) offs[NN] = carry;
}

__global__ void scatter_kernel(EdgePtrs ep, const float* __restrict__ pbuf,
                               const float* __restrict__ s, int* __restrict__ cursor,
                               int4* __restrict__ recs) {
    int i = blockIdx.x * 256 + threadIdx.x;
    if (i >= NR * EE) return;
    int r = i / EE, ei = i - r * EE;
    int sN = ep.e[r][ei];
    int d = ep.e[r][EE + ei];
    int slot = atomicAdd(&cursor[d], 1);
    float a0 = pbuf[(size_t)i * 2 + 0] / (s[(r * NN + d) * 2 + 0] + 1e-16f);
    float a1 = pbuf[(size_t)i * 2 + 1] / (s[(r * NN + d) * 2 + 1] + 1e-16f);
    int4 rec;
    rec.x = sN;
    rec.y = __float_as_int(a0);
    rec.z = __float_as_int(a1);
    rec.w = 0;
    recs[slot] = rec;
}

// CT = H*C floats per row; one block per dst node; float4 per thread
template <int CT, bool RELU>
__global__ void aggregate_kernel(const float* __restrict__ xs, const int4* __restrict__ recs,
                                 const int* __restrict__ offs, const float* __restrict__ lself,
                                 const unsigned* __restrict__ m, const float* __restrict__ s,
                                 const float* __restrict__ bias, float* __restrict__ out) {
    constexpr int T = CT / 4;
    int n = blockIdx.x;
    int t = threadIdx.x;
    int h = (t >= T / 2) ? 1 : 0;
    float l = lself[n * 2 + h];
    float coef = 0.f;
    for (int r = 0; r < NR; ++r) {
        int idx = (r * NN + n) * 2 + h;
        coef += expf(l - o2f(m[idx])) / (s[idx] + 1e-16f);
    }
    float4 xv = *(const float4*)&xs[(size_t)n * CT + t * 4];
    float4 bv = *(const float4*)&bias[t * 4];
    float4 acc;
    acc.x = coef * xv.x + 6.f * bv.x;
    acc.y = coef * xv.y + 6.f * bv.y;
    acc.z = coef * xv.z + 6.f * bv.z;
    acc.w = coef * xv.w + 6.f * bv.w;
    int beg = offs[n], end = offs[n + 1];
    for (int j = beg; j < end; ++j) {
        int4 rec = recs[j];
        float alpha = h ? __int_as_float(rec.z) : __int_as_float(rec.y);
        const float4 v = *(const float4*)&xs[(size_t)rec.x * CT + t * 4];
        acc.x = fmaf(alpha, v.x, acc.x);
        acc.y = fmaf(alpha, v.y, acc.y);
        acc.z = fmaf(alpha, v.z, acc.z);
        acc.w = fmaf(alpha, v.w, acc.w);
    }
    if (RELU) {
        acc.x = fmaxf(acc.x, 0.f); acc.y = fmaxf(acc.y, 0.f);
        acc.z = fmaxf(acc.z, 0.f); acc.w = fmaxf(acc.w, 0.f);
    }
    *(float4*)&out[(size_t)n * CT + t * 4] = acc;
}

extern "C" void kernel_launch(void* const* d_in, const int* in_sizes, int n_in,
                              void* d_out, int out_size, void* d_ws, size_t ws_size,
                              hipStream_t stream) {
    const float* x = (const float*)d_in[0];
    EdgePtrs ep;
    for (int r = 0; r < NR; ++r) ep.e[r] = (const int*)d_in[1 + r];
    const float* W1s = (const float*)d_in[7];
    const float* W1d = (const float*)d_in[8];
    const float* a1s = (const float*)d_in[9];
    const float* a1d = (const float*)d_in[10];
    const float* b1  = (const float*)d_in[11];
    const float* W2s = (const float*)d_in[12];
    const float* W2d = (const float*)d_in[13];
    const float* a2s = (const float*)d_in[14];
    const float* a2d = (const float*)d_in[15];
    const float* b2  = (const float*)d_in[16];
    float* out = (float*)d_out;

    char* base = (char*)d_ws;
    size_t off = 0;
    auto take = [&](size_t nbytes) -> void* {
        void* p = base + off;
        off = (off + nbytes + 255) & ~(size_t)255;
        return p;
    };
    float* xs1   = (float*)take((size_t)NN * 1024 * 4);
    float* h1    = (float*)take((size_t)NN * 1024 * 4);
    float* xs2   = xs1;  // layer-2 gemm output reuses xs1 space (dead after L1 aggregate)
    float* alsrc = (float*)take((size_t)NN * HH * 4);
    float* aldst = (float*)take((size_t)NN * HH * 4);
    float* lself = (float*)take((size_t)NN * HH * 4);
    unsigned* m  = (unsigned*)take((size_t)NR * NN * HH * 4);
    float* s     = (float*)take((size_t)NR * NN * HH * 4);
    float* pbuf  = (float*)take((size_t)NR * EE * HH * 4);
    int* count   = (int*)take((size_t)NN * 4);
    int* offs    = (int*)take((size_t)(NN + 1) * 4);
    int* cursor  = (int*)take((size_t)NN * 4);
    int4* recs   = (int4*)take((size_t)NR * EE * 16);
    float* wts   = (float*)take((size_t)HH * 1024 * 4);
    float* wtd   = (float*)take((size_t)HH * 1024 * 4);

    const int EB = (NR * EE + 255) / 256;      // edge-kernel blocks
    const int SB = (NR * NN * HH + 255) / 256; // s_init blocks

    // ---------------- Layer 1: K=512, C=512, Nout=1024 ----------------
    {
        const int K = 512, C = 512, Nout = 1024;
        fold_a_kernel<<<dim3((K + 255) / 256, HH), 256, 0, stream>>>(W1s, a1s, wts, C, K);
        fold_a_kernel<<<dim3((K + 255) / 256, HH), 256, 0, stream>>>(W1d, a1d, wtd, C, K);
        gemm_nt<<<dim3(Nout / 64, (NN + 63) / 64), 256, 0, stream>>>(x, W1s, xs1, NN, Nout, K);
        al_kernel<<<NN, 256, 0, stream>>>(x, wts, wtd, K, alsrc, aldst, lself, m, count);
        edge_logit_max<<<EB, 256, 0, stream>>>(ep, alsrc, aldst, pbuf, m, count);
        s_init_kernel<<<SB, 256, 0, stream>>>(lself, m, s);
        edge_p_sum<<<EB, 256, 0, stream>>>(ep, m, pbuf, s);
        scan_kernel<<<1, 1024, 0, stream>>>(count, offs, cursor);
        scatter_kernel<<<EB, 256, 0, stream>>>(ep, pbuf, s, cursor, recs);
        aggregate_kernel<1024, true><<<NN, 256, 0, stream>>>(xs1, recs, offs, lself, m, s, b1, h1);
    }
    // ---------------- Layer 2: K=1024, C=128, Nout=256 ----------------
    {
        const int K = 1024, C = 128, Nout = 256;
        fold_a_kernel<<<dim3((K + 255) / 256, HH), 256, 0, stream>>>(W2s, a2s, wts, C, K);
        fold_a_kernel<<<dim3((K + 255) / 256, HH), 256, 0, stream>>>(W2d, a2d, wtd, C, K);
        gemm_nt<<<dim3(Nout / 64, (NN + 63) / 64), 256, 0, stream>>>(h1, W2s, xs2, NN, Nout, K);
        al_kernel<<<NN, 256, 0, stream>>>(h1, wts, wtd, K, alsrc, aldst, lself, m, count);
        edge_logit_max<<<EB, 256, 0, stream>>>(ep, alsrc, aldst, pbuf, m, count);
        s_init_kernel<<<SB, 256, 0, stream>>>(lself, m, s);
        edge_p_sum<<<EB, 256, 0, stream>>>(ep, m, pbuf, s);
        scan_kernel<<<1, 1024, 0, stream>>>(count, offs, cursor);
        scatter_kernel<<<EB, 256, 0, stream>>>(ep, pbuf, s, cursor, recs);
        aggregate_kernel<256, false><<<NN, 64, 0, stream>>>(xs2, recs, offs, lself, m, s, b2, out);
    }
}

// Round 3
// 1091.455 us; speedup vs baseline: 1.5890x; 1.5890x over previous
//
#include <hip/hip_runtime.h>
#include <cstddef>

#define NN 20000
#define EE 100000
#define NR 6
#define HH 2
#define NEG 0.2f

struct EdgePtrs { const int* e[NR]; };

typedef __attribute__((ext_vector_type(8))) short bf16x8;
typedef __attribute__((ext_vector_type(4))) float f32x4;

__device__ __forceinline__ unsigned f2o(float f) {
    unsigned u = __float_as_uint(f);
    return (u & 0x80000000u) ? ~u : (u | 0x80000000u);
}
__device__ __forceinline__ float o2f(unsigned u) {
    return (u & 0x80000000u) ? __uint_as_float(u & 0x7fffffffu) : __uint_as_float(~u);
}
__device__ __forceinline__ unsigned short rnebf(float f) {
    unsigned u = __float_as_uint(f);
    return (unsigned short)((u + 0x7fffu + ((u >> 16) & 1u)) >> 16);
}
__device__ __forceinline__ float b2f(unsigned short b) {
    return __uint_as_float(((unsigned)b) << 16);
}
__device__ __forceinline__ void unpack8(uint4 v, float* f) {
    f[0] = __uint_as_float(v.x << 16); f[1] = __uint_as_float(v.x & 0xffff0000u);
    f[2] = __uint_as_float(v.y << 16); f[3] = __uint_as_float(v.y & 0xffff0000u);
    f[4] = __uint_as_float(v.z << 16); f[5] = __uint_as_float(v.z & 0xffff0000u);
    f[6] = __uint_as_float(v.w << 16); f[7] = __uint_as_float(v.w & 0xffff0000u);
}
__device__ __forceinline__ unsigned pack2(float a, float b) {
    return (unsigned)rnebf(a) | ((unsigned)rnebf(b) << 16);
}
__device__ __forceinline__ void glld16(unsigned short* lds, const void* g) {
    __builtin_amdgcn_global_load_lds(
        (const __attribute__((address_space(1))) unsigned int*)g,
        (__attribute__((address_space(3))) unsigned int*)lds, 16, 0, 0);
}

// fp32 -> bf16 RNE, 4 elems/thread
__global__ void f2b_kernel(const float* __restrict__ in, unsigned short* __restrict__ out, int n) {
    int i = (blockIdx.x * 256 + threadIdx.x) * 4;
    if (i >= n) return;
    float4 v = *(const float4*)&in[i];
    unsigned short o[4] = {rnebf(v.x), rnebf(v.y), rnebf(v.z), rnebf(v.w)};
    *(uint2*)&out[i] = *(uint2*)o;
}

// w~[h][k] = sum_c a[h,c] * W[h*C+c, k]
__global__ void fold_a_kernel(const float* __restrict__ W, const float* __restrict__ a,
                              float* __restrict__ wt, int C, int K) {
    int k = blockIdx.x * 256 + threadIdx.x;
    int h = blockIdx.y;
    if (k >= K) return;
    float acc = 0.f;
    for (int c = 0; c < C; ++c)
        acc = fmaf(a[h * C + c], W[(size_t)(h * C + c) * K + k], acc);
    wt[h * K + k] = acc;
}

// C[M][Nn] = A[M][K] @ B[Nn][K]^T, bf16 in, bf16 out, fp32 accum (MFMA 16x16x32)
// 128x128 tile, BK=32, 4 waves (2x2), 4x4 frags/wave, global_load_lds w/ pre-swizzled src
__global__ __launch_bounds__(256) void gemm_nt_mfma(
    const unsigned short* __restrict__ A, const unsigned short* __restrict__ B,
    unsigned short* __restrict__ C, int M, int Nn, int K) {
    __shared__ unsigned short As[128 * 32];
    __shared__ unsigned short Bs[128 * 32];
    const int tid = threadIdx.x;
    const int lane = tid & 63;
    const int wave = tid >> 6;
    const int wr = wave >> 1, wc = wave & 1;
    const int row0 = blockIdx.y * 128, col0 = blockIdx.x * 128;

    f32x4 acc[4][4];
#pragma unroll
    for (int i = 0; i < 4; ++i)
#pragma unroll
        for (int j = 0; j < 4; ++j) acc[i][j] = (f32x4){0.f, 0.f, 0.f, 0.f};

    // staging: thread covers LDS bytes [tid*16 + c*4096, +16), c=0,1
    // -> row = tid/4 + c*64, slot = tid%3..  (tid&3); swizzle slot ^= row&3
    const int srow = tid >> 2;
    const int slot = tid & 3;
    const int sw = ((slot ^ (srow & 3)) << 4);  // byte offset in 64B row window
    int ar0 = row0 + srow;        if (ar0 >= M) ar0 = M - 1;
    int ar1 = row0 + srow + 64;   if (ar1 >= M) ar1 = M - 1;
    const int br0 = col0 + srow;
    const int br1 = col0 + srow + 64;

    const int q = lane >> 4;
    for (int k0 = 0; k0 < K; k0 += 32) {
        glld16(As + tid * 8,        (const char*)A + ((size_t)ar0 * K + k0) * 2 + sw);
        glld16(As + tid * 8 + 2048, (const char*)A + ((size_t)ar1 * K + k0) * 2 + sw);
        glld16(Bs + tid * 8,        (const char*)B + ((size_t)br0 * K + k0) * 2 + sw);
        glld16(Bs + tid * 8 + 2048, (const char*)B + ((size_t)br1 * K + k0) * 2 + sw);
        __syncthreads();
        bf16x8 af[4], bfr[4];
#pragma unroll
        for (int m = 0; m < 4; ++m) {
            int r = wr * 64 + m * 16 + (lane & 15);
            af[m] = *(const bf16x8*)&As[r * 32 + ((q ^ (r & 3)) << 3)];
        }
#pragma unroll
        for (int nI = 0; nI < 4; ++nI) {
            int c = wc * 64 + nI * 16 + (lane & 15);
            bfr[nI] = *(const bf16x8*)&Bs[c * 32 + ((q ^ (c & 3)) << 3)];
        }
#pragma unroll
        for (int m = 0; m < 4; ++m)
#pragma unroll
            for (int nI = 0; nI < 4; ++nI)
                acc[m][nI] = __builtin_amdgcn_mfma_f32_16x16x32_bf16(af[m], bfr[nI], acc[m][nI], 0, 0, 0);
        __syncthreads();
    }
    const int crow = (lane >> 4) * 4;
    const int ccol = lane & 15;
#pragma unroll
    for (int m = 0; m < 4; ++m)
#pragma unroll
        for (int nI = 0; nI < 4; ++nI)
#pragma unroll
            for (int j = 0; j < 4; ++j) {
                int r = row0 + wr * 64 + m * 16 + crow + j;
                int c = col0 + wc * 64 + nI * 16 + ccol;
                if (r < M) C[(size_t)r * Nn + c] = rnebf(acc[m][nI][j]);
            }
}

// per node: al_src/al_dst from bf16 x, l_self, init m for all relations, zero count
__global__ void al_kernel_b(const unsigned short* __restrict__ x, const float* __restrict__ wts,
                            const float* __restrict__ wtd, int K,
                            float* __restrict__ al_src, float* __restrict__ al_dst,
                            float* __restrict__ lself, unsigned* __restrict__ m,
                            int* __restrict__ count) {
    int n = blockIdx.x;
    int tid = threadIdx.x;
    __shared__ float red[4][256];
    float p0 = 0.f, p1 = 0.f, p2 = 0.f, p3 = 0.f;
    for (int k = tid; k < K; k += 256) {
        float xv = b2f(x[(size_t)n * K + k]);
        p0 = fmaf(xv, wts[k], p0);
        p1 = fmaf(xv, wts[K + k], p1);
        p2 = fmaf(xv, wtd[k], p2);
        p3 = fmaf(xv, wtd[K + k], p3);
    }
    red[0][tid] = p0; red[1][tid] = p1; red[2][tid] = p2; red[3][tid] = p3;
    __syncthreads();
    for (int st = 128; st > 0; st >>= 1) {
        if (tid < st) {
            for (int qq = 0; qq < 4; ++qq) red[qq][tid] += red[qq][tid + st];
        }
        __syncthreads();
    }
    if (tid == 0) {
        for (int h = 0; h < HH; ++h) {
            float as_ = red[h][0], ad_ = red[2 + h][0];
            al_src[n * HH + h] = as_;
            al_dst[n * HH + h] = ad_;
            float l = as_ + ad_;
            l = l > 0.f ? l : NEG * l;
            lself[n * HH + h] = l;
            unsigned enc = f2o(l);
            for (int r = 0; r < NR; ++r) m[(r * NN + n) * HH + h] = enc;
        }
        count[n] = 0;
    }
}

__global__ void edge_logit_max(EdgePtrs ep, const float* __restrict__ al_src,
                               const float* __restrict__ al_dst,
                               float* __restrict__ pbuf, unsigned* __restrict__ m,
                               int* __restrict__ count) {
    int i = blockIdx.x * 256 + threadIdx.x;
    if (i >= NR * EE) return;
    int r = i / EE, ei = i - r * EE;
    const int* e = ep.e[r];
    int sN = e[ei];
    int d = e[EE + ei];
    float l0 = al_src[sN * 2 + 0] + al_dst[d * 2 + 0]; l0 = l0 > 0.f ? l0 : NEG * l0;
    float l1 = al_src[sN * 2 + 1] + al_dst[d * 2 + 1]; l1 = l1 > 0.f ? l1 : NEG * l1;
    pbuf[(size_t)i * 2 + 0] = l0;
    pbuf[(size_t)i * 2 + 1] = l1;
    atomicMax(&m[(r * NN + d) * 2 + 0], f2o(l0));
    atomicMax(&m[(r * NN + d) * 2 + 1], f2o(l1));
    atomicAdd(&count[d], 1);
}

__global__ void s_init_kernel(const float* __restrict__ lself, const unsigned* __restrict__ m,
                              float* __restrict__ s) {
    int i = blockIdx.x * 256 + threadIdx.x;
    if (i >= NR * NN * HH) return;
    int nh = i % (NN * HH);
    s[i] = expf(lself[nh] - o2f(m[i]));
}

__global__ void edge_p_sum(EdgePtrs ep, const unsigned* __restrict__ m,
                           float* __restrict__ pbuf, float* __restrict__ s) {
    int i = blockIdx.x * 256 + threadIdx.x;
    if (i >= NR * EE) return;
    int r = i / EE, ei = i - r * EE;
    int d = ep.e[r][EE + ei];
    float p0 = expf(pbuf[(size_t)i * 2 + 0] - o2f(m[(r * NN + d) * 2 + 0]));
    float p1 = expf(pbuf[(size_t)i * 2 + 1] - o2f(m[(r * NN + d) * 2 + 1]));
    pbuf[(size_t)i * 2 + 0] = p0;
    pbuf[(size_t)i * 2 + 1] = p1;
    atomicAdd(&s[(r * NN + d) * 2 + 0], p0);
    atomicAdd(&s[(r * NN + d) * 2 + 1], p1);
}

__global__ void scan_kernel(const int* __restrict__ count, int* __restrict__ offs,
                            int* __restrict__ cursor) {
    __shared__ int sh[1024];
    __shared__ int carry;
    int tid = threadIdx.x;
    if (tid == 0) carry = 0;
    __syncthreads();
    for (int base = 0; base < NN; base += 1024) {
        int v = (base + tid < NN) ? count[base + tid] : 0;
        sh[tid] = v;
        __syncthreads();
        for (int st = 1; st < 1024; st <<= 1) {
            int t = (tid >= st) ? sh[tid - st] : 0;
            __syncthreads();
            sh[tid] += t;
            __syncthreads();
        }
        int excl = sh[tid] - v + carry;
        if (base + tid < NN) { offs[base + tid] = excl; cursor[base + tid] = excl; }
        __syncthreads();
        if (tid == 0) carry += sh[1023];
        __syncthreads();
    }
    if (tid == 0) offs[NN] = carry;
}

__global__ void scatter_kernel(EdgePtrs ep, const float* __restrict__ pbuf,
                               const float* __restrict__ s, int* __restrict__ cursor,
                               int4* __restrict__ recs) {
    int i = blockIdx.x * 256 + threadIdx.x;
    if (i >= NR * EE) return;
    int r = i / EE, ei = i - r * EE;
    int sN = ep.e[r][ei];
    int d = ep.e[r][EE + ei];
    int slot = atomicAdd(&cursor[d], 1);
    float a0 = pbuf[(size_t)i * 2 + 0] / (s[(r * NN + d) * 2 + 0] + 1e-16f);
    float a1 = pbuf[(size_t)i * 2 + 1] / (s[(r * NN + d) * 2 + 1] + 1e-16f);
    int4 rec;
    rec.x = sN;
    rec.y = __float_as_int(a0);
    rec.z = __float_as_int(a1);
    rec.w = 0;
    recs[slot] = rec;
}

// L1 aggregate: 1024 ch, bf16 in/out, relu. 128 threads x 8 ch.
__global__ void aggregate_l1(const unsigned short* __restrict__ xs, const int4* __restrict__ recs,
                             const int* __restrict__ offs, const float* __restrict__ lself,
                             const unsigned* __restrict__ m, const float* __restrict__ s,
                             const float* __restrict__ bias, unsigned short* __restrict__ out) {
    int n = blockIdx.x;
    int t = threadIdx.x;
    int h = t >> 6;
    float l = lself[n * 2 + h];
    float coef = 0.f;
    for (int r = 0; r < NR; ++r) {
        int idx = (r * NN + n) * 2 + h;
        coef += expf(l - o2f(m[idx])) / (s[idx] + 1e-16f);
    }
    float acc[8], f[8];
    uint4 sv = *(const uint4*)&xs[(size_t)n * 1024 + t * 8];
    unpack8(sv, f);
#pragma unroll
    for (int j = 0; j < 8; ++j) acc[j] = coef * f[j] + 6.f * bias[t * 8 + j];
    int beg = offs[n], end = offs[n + 1];
    int4 rec;
    if (beg < end) rec = recs[beg];
    for (int j = beg; j < end; ++j) {
        int4 cur = rec;
        if (j + 1 < end) rec = recs[j + 1];
        float alpha = h ? __int_as_float(cur.z) : __int_as_float(cur.y);
        uint4 v = *(const uint4*)&xs[(size_t)cur.x * 1024 + t * 8];
        unpack8(v, f);
#pragma unroll
        for (int jj = 0; jj < 8; ++jj) acc[jj] = fmaf(alpha, f[jj], acc[jj]);
    }
#pragma unroll
    for (int j = 0; j < 8; ++j) acc[j] = fmaxf(acc[j], 0.f);
    uint4 o;
    o.x = pack2(acc[0], acc[1]); o.y = pack2(acc[2], acc[3]);
    o.z = pack2(acc[4], acc[5]); o.w = pack2(acc[6], acc[7]);
    *(uint4*)&out[(size_t)n * 1024 + t * 8] = o;
}

// L2 aggregate: 256 ch, bf16 in, fp32 out, no relu. 64 threads x 4 ch.
__global__ void aggregate_l2(const unsigned short* __restrict__ xs, const int4* __restrict__ recs,
                             const int* __restrict__ offs, const float* __restrict__ lself,
                             const unsigned* __restrict__ m, const float* __restrict__ s,
                             const float* __restrict__ bias, float* __restrict__ out) {
    int n = blockIdx.x;
    int t = threadIdx.x;
    int h = t >> 5;
    float l = lself[n * 2 + h];
    float coef = 0.f;
    for (int r = 0; r < NR; ++r) {
        int idx = (r * NN + n) * 2 + h;
        coef += expf(l - o2f(m[idx])) / (s[idx] + 1e-16f);
    }
    float acc[4];
    uint2 sv = *(const uint2*)&xs[(size_t)n * 256 + t * 4];
    float f0 = __uint_as_float(sv.x << 16), f1 = __uint_as_float(sv.x & 0xffff0000u);
    float f2 = __uint_as_float(sv.y << 16), f3 = __uint_as_float(sv.y & 0xffff0000u);
    acc[0] = coef * f0 + 6.f * bias[t * 4 + 0];
    acc[1] = coef * f1 + 6.f * bias[t * 4 + 1];
    acc[2] = coef * f2 + 6.f * bias[t * 4 + 2];
    acc[3] = coef * f3 + 6.f * bias[t * 4 + 3];
    int beg = offs[n], end = offs[n + 1];
    int4 rec;
    if (beg < end) rec = recs[beg];
    for (int j = beg; j < end; ++j) {
        int4 cur = rec;
        if (j + 1 < end) rec = recs[j + 1];
        float alpha = h ? __int_as_float(cur.z) : __int_as_float(cur.y);
        uint2 v = *(const uint2*)&xs[(size_t)cur.x * 256 + t * 4];
        acc[0] = fmaf(alpha, __uint_as_float(v.x << 16), acc[0]);
        acc[1] = fmaf(alpha, __uint_as_float(v.x & 0xffff0000u), acc[1]);
        acc[2] = fmaf(alpha, __uint_as_float(v.y << 16), acc[2]);
        acc[3] = fmaf(alpha, __uint_as_float(v.y & 0xffff0000u), acc[3]);
    }
    float4 o = make_float4(acc[0], acc[1], acc[2], acc[3]);
    *(float4*)&out[(size_t)n * 256 + t * 4] = o;
}

extern "C" void kernel_launch(void* const* d_in, const int* in_sizes, int n_in,
                              void* d_out, int out_size, void* d_ws, size_t ws_size,
                              hipStream_t stream) {
    const float* x = (const float*)d_in[0];
    EdgePtrs ep;
    for (int r = 0; r < NR; ++r) ep.e[r] = (const int*)d_in[1 + r];
    const float* W1s = (const float*)d_in[7];
    const float* a1s = (const float*)d_in[9];
    const float* a1d = (const float*)d_in[10];
    const float* b1  = (const float*)d_in[11];
    const float* W2s = (const float*)d_in[12];
    const float* a2s = (const float*)d_in[14];
    const float* a2d = (const float*)d_in[15];
    const float* b2  = (const float*)d_in[16];
    const float* W1d = (const float*)d_in[8];
    const float* W2d = (const float*)d_in[13];
    float* out = (float*)d_out;

    char* base = (char*)d_ws;
    size_t off = 0;
    auto take = [&](size_t nbytes) -> void* {
        void* p = base + off;
        off = (off + nbytes + 255) & ~(size_t)255;
        return p;
    };
    unsigned short* xb   = (unsigned short*)take((size_t)NN * 512 * 2);
    unsigned short* xs1b = (unsigned short*)take((size_t)NN * 1024 * 2);
    unsigned short* h1b  = (unsigned short*)take((size_t)NN * 1024 * 2);
    unsigned short* xs2b = xs1b;  // reuse (xs1 dead after L1 aggregate)
    unsigned short* Wb   = (unsigned short*)take((size_t)1024 * 512 * 2);
    float* alsrc = (float*)take((size_t)NN * HH * 4);
    float* aldst = (float*)take((size_t)NN * HH * 4);
    float* lself = (float*)take((size_t)NN * HH * 4);
    unsigned* m  = (unsigned*)take((size_t)NR * NN * HH * 4);
    float* s     = (float*)take((size_t)NR * NN * HH * 4);
    float* pbuf  = (float*)take((size_t)NR * EE * HH * 4);
    int* count   = (int*)take((size_t)NN * 4);
    int* offs    = (int*)take((size_t)(NN + 1) * 4);
    int* cursor  = (int*)take((size_t)NN * 4);
    int4* recs   = (int4*)take((size_t)NR * EE * 16);
    float* wts   = (float*)take((size_t)HH * 1024 * 4);
    float* wtd   = (float*)take((size_t)HH * 1024 * 4);

    const int EB = (NR * EE + 255) / 256;
    const int SB = (NR * NN * HH + 255) / 256;

    // ---------------- Layer 1: K=512, C=512, Nout=1024 ----------------
    {
        const int K = 512, C = 512, Nout = 1024;
        f2b_kernel<<<(NN * 512 / 4 + 255) / 256, 256, 0, stream>>>(x, xb, NN * 512);
        f2b_kernel<<<(Nout * K / 4 + 255) / 256, 256, 0, stream>>>(W1s, Wb, Nout * K);
        fold_a_kernel<<<dim3((K + 255) / 256, HH), 256, 0, stream>>>(W1s, a1s, wts, C, K);
        fold_a_kernel<<<dim3((K + 255) / 256, HH), 256, 0, stream>>>(W1d, a1d, wtd, C, K);
        gemm_nt_mfma<<<dim3(Nout / 128, (NN + 127) / 128), 256, 0, stream>>>(xb, Wb, xs1b, NN, Nout, K);
        al_kernel_b<<<NN, 256, 0, stream>>>(xb, wts, wtd, K, alsrc, aldst, lself, m, count);
        edge_logit_max<<<EB, 256, 0, stream>>>(ep, alsrc, aldst, pbuf, m, count);
        s_init_kernel<<<SB, 256, 0, stream>>>(lself, m, s);
        edge_p_sum<<<EB, 256, 0, stream>>>(ep, m, pbuf, s);
        scan_kernel<<<1, 1024, 0, stream>>>(count, offs, cursor);
        scatter_kernel<<<EB, 256, 0, stream>>>(ep, pbuf, s, cursor, recs);
        aggregate_l1<<<NN, 128, 0, stream>>>(xs1b, recs, offs, lself, m, s, b1, h1b);
    }
    // ---------------- Layer 2: K=1024, C=128, Nout=256 ----------------
    {
        const int K = 1024, C = 128, Nout = 256;
        f2b_kernel<<<(Nout * K / 4 + 255) / 256, 256, 0, stream>>>(W2s, Wb, Nout * K);
        fold_a_kernel<<<dim3((K + 255) / 256, HH), 256, 0, stream>>>(W2s, a2s, wts, C, K);
        fold_a_kernel<<<dim3((K + 255) / 256, HH), 256, 0, stream>>>(W2d, a2d, wtd, C, K);
        gemm_nt_mfma<<<dim3(Nout / 128, (NN + 127) / 128), 256, 0, stream>>>(h1b, Wb, xs2b, NN, Nout, K);
        al_kernel_b<<<NN, 256, 0, stream>>>(h1b, wts, wtd, K, alsrc, aldst, lself, m, count);
        edge_logit_max<<<EB, 256, 0, stream>>>(ep, alsrc, aldst, pbuf, m, count);
        s_init_kernel<<<SB, 256, 0, stream>>>(lself, m, s);
        edge_p_sum<<<EB, 256, 0, stream>>>(ep, m, pbuf, s);
        scan_kernel<<<1, 1024, 0, stream>>>(count, offs, cursor);
        scatter_kernel<<<EB, 256, 0, stream>>>(ep, pbuf, s, cursor, recs);
        aggregate_l2<<<NN, 64, 0, stream>>>(xs2b, recs, offs, lself, m, s, b2, out);
    }
}

// Round 4
// 880.550 us; speedup vs baseline: 1.9696x; 1.2395x over previous
//
#include <hip/hip_runtime.h>
#include <cstddef>

#define NN 20000
#define EE 100000
#define NR 6
#define HH 2
#define NEG 0.2f

struct EdgePtrs { const int* e[NR]; };

typedef __attribute__((ext_vector_type(8))) short bf16x8;
typedef __attribute__((ext_vector_type(4))) float f32x4;

__device__ __forceinline__ unsigned f2o(float f) {
    unsigned u = __float_as_uint(f);
    return (u & 0x80000000u) ? ~u : (u | 0x80000000u);
}
__device__ __forceinline__ float o2f(unsigned u) {
    return (u & 0x80000000u) ? __uint_as_float(u & 0x7fffffffu) : __uint_as_float(~u);
}
__device__ __forceinline__ unsigned short rnebf(float f) {
    unsigned u = __float_as_uint(f);
    return (unsigned short)((u + 0x7fffu + ((u >> 16) & 1u)) >> 16);
}
__device__ __forceinline__ float b2f(unsigned short b) {
    return __uint_as_float(((unsigned)b) << 16);
}
__device__ __forceinline__ void unpack8(uint4 v, float* f) {
    f[0] = __uint_as_float(v.x << 16); f[1] = __uint_as_float(v.x & 0xffff0000u);
    f[2] = __uint_as_float(v.y << 16); f[3] = __uint_as_float(v.y & 0xffff0000u);
    f[4] = __uint_as_float(v.z << 16); f[5] = __uint_as_float(v.z & 0xffff0000u);
    f[6] = __uint_as_float(v.w << 16); f[7] = __uint_as_float(v.w & 0xffff0000u);
}
__device__ __forceinline__ unsigned pack2(float a, float b) {
    return (unsigned)rnebf(a) | ((unsigned)rnebf(b) << 16);
}
__device__ __forceinline__ void glld16(unsigned short* lds, const void* g) {
    __builtin_amdgcn_global_load_lds(
        (const __attribute__((address_space(1))) unsigned int*)g,
        (__attribute__((address_space(3))) unsigned int*)lds, 16, 0, 0);
}

// fp32 -> bf16 RNE, 4 elems/thread
__global__ void f2b_kernel(const float* __restrict__ in, unsigned short* __restrict__ out, int n) {
    int i = (blockIdx.x * 256 + threadIdx.x) * 4;
    if (i >= n) return;
    float4 v = *(const float4*)&in[i];
    unsigned short o[4] = {rnebf(v.x), rnebf(v.y), rnebf(v.z), rnebf(v.w)};
    *(uint2*)&out[i] = *(uint2*)o;
}

// wt[h][k] = sum_c a[h,c] * W[h*C+c, k]
// grid (K/64, H), block 256: thread -> k = bx*64 + tid&63, c-part = tid>>6 (4 parts)
__global__ void fold_a_kernel(const float* __restrict__ W, const float* __restrict__ a,
                              float* __restrict__ wt, int C, int K) {
    __shared__ float red[256];
    int h = blockIdx.y;
    int k = blockIdx.x * 64 + (threadIdx.x & 63);
    int cp = threadIdx.x >> 6;
    float acc = 0.f;
    for (int c = cp; c < C; c += 4)
        acc = fmaf(a[h * C + c], W[(size_t)(h * C + c) * K + k], acc);
    red[threadIdx.x] = acc;
    __syncthreads();
    if (cp == 0) {
        acc = red[threadIdx.x] + red[threadIdx.x + 64] +
              red[threadIdx.x + 128] + red[threadIdx.x + 192];
        wt[h * K + k] = acc;
    }
}

// C[M][Nn] = A[M][K] @ B[Nn][K]^T, bf16 in, bf16 out, fp32 accum (MFMA 16x16x32)
// 128x128 tile, BK=32, 4 waves (2x2), 4x4 frags/wave, global_load_lds w/ pre-swizzled src
__global__ __launch_bounds__(256) void gemm_nt_mfma(
    const unsigned short* __restrict__ A, const unsigned short* __restrict__ B,
    unsigned short* __restrict__ C, int M, int Nn, int K) {
    __shared__ unsigned short As[128 * 32];
    __shared__ unsigned short Bs[128 * 32];
    const int tid = threadIdx.x;
    const int lane = tid & 63;
    const int wave = tid >> 6;
    const int wr = wave >> 1, wc = wave & 1;
    const int row0 = blockIdx.y * 128, col0 = blockIdx.x * 128;

    f32x4 acc[4][4];
#pragma unroll
    for (int i = 0; i < 4; ++i)
#pragma unroll
        for (int j = 0; j < 4; ++j) acc[i][j] = (f32x4){0.f, 0.f, 0.f, 0.f};

    const int srow = tid >> 2;
    const int slot = tid & 3;
    const int sw = ((slot ^ (srow & 3)) << 4);
    int ar0 = row0 + srow;        if (ar0 >= M) ar0 = M - 1;
    int ar1 = row0 + srow + 64;   if (ar1 >= M) ar1 = M - 1;
    const int br0 = col0 + srow;
    const int br1 = col0 + srow + 64;

    const int q = lane >> 4;
    for (int k0 = 0; k0 < K; k0 += 32) {
        glld16(As + tid * 8,        (const char*)A + ((size_t)ar0 * K + k0) * 2 + sw);
        glld16(As + tid * 8 + 2048, (const char*)A + ((size_t)ar1 * K + k0) * 2 + sw);
        glld16(Bs + tid * 8,        (const char*)B + ((size_t)br0 * K + k0) * 2 + sw);
        glld16(Bs + tid * 8 + 2048, (const char*)B + ((size_t)br1 * K + k0) * 2 + sw);
        __syncthreads();
        bf16x8 af[4], bfr[4];
#pragma unroll
        for (int m = 0; m < 4; ++m) {
            int r = wr * 64 + m * 16 + (lane & 15);
            af[m] = *(const bf16x8*)&As[r * 32 + ((q ^ (r & 3)) << 3)];
        }
#pragma unroll
        for (int nI = 0; nI < 4; ++nI) {
            int c = wc * 64 + nI * 16 + (lane & 15);
            bfr[nI] = *(const bf16x8*)&Bs[c * 32 + ((q ^ (c & 3)) << 3)];
        }
#pragma unroll
        for (int m = 0; m < 4; ++m)
#pragma unroll
            for (int nI = 0; nI < 4; ++nI)
                acc[m][nI] = __builtin_amdgcn_mfma_f32_16x16x32_bf16(af[m], bfr[nI], acc[m][nI], 0, 0, 0);
        __syncthreads();
    }
    const int crow = (lane >> 4) * 4;
    const int ccol = lane & 15;
#pragma unroll
    for (int m = 0; m < 4; ++m)
#pragma unroll
        for (int nI = 0; nI < 4; ++nI)
#pragma unroll
            for (int j = 0; j < 4; ++j) {
                int r = row0 + wr * 64 + m * 16 + crow + j;
                int c = col0 + wc * 64 + nI * 16 + ccol;
                if (r < M) C[(size_t)r * Nn + c] = rnebf(acc[m][nI][j]);
            }
}

// per node: al_src/al_dst from bf16 x, l_self, init m for all relations, zero count
__global__ void al_kernel_b(const unsigned short* __restrict__ x, const float* __restrict__ wts,
                            const float* __restrict__ wtd, int K,
                            float* __restrict__ al_src, float* __restrict__ al_dst,
                            float* __restrict__ lself, unsigned* __restrict__ m,
                            int* __restrict__ count) {
    int n = blockIdx.x;
    int tid = threadIdx.x;
    __shared__ float red[4][256];
    float p0 = 0.f, p1 = 0.f, p2 = 0.f, p3 = 0.f;
    for (int k = tid; k < K; k += 256) {
        float xv = b2f(x[(size_t)n * K + k]);
        p0 = fmaf(xv, wts[k], p0);
        p1 = fmaf(xv, wts[K + k], p1);
        p2 = fmaf(xv, wtd[k], p2);
        p3 = fmaf(xv, wtd[K + k], p3);
    }
    red[0][tid] = p0; red[1][tid] = p1; red[2][tid] = p2; red[3][tid] = p3;
    __syncthreads();
    for (int st = 128; st > 0; st >>= 1) {
        if (tid < st) {
            for (int qq = 0; qq < 4; ++qq) red[qq][tid] += red[qq][tid + st];
        }
        __syncthreads();
    }
    if (tid == 0) {
        for (int h = 0; h < HH; ++h) {
            float as_ = red[h][0], ad_ = red[2 + h][0];
            al_src[n * HH + h] = as_;
            al_dst[n * HH + h] = ad_;
            float l = as_ + ad_;
            l = l > 0.f ? l : NEG * l;
            lself[n * HH + h] = l;
            unsigned enc = f2o(l);
            for (int r = 0; r < NR; ++r) m[(r * NN + n) * HH + h] = enc;
        }
        count[n] = 0;
    }
}

__global__ void edge_logit_max(EdgePtrs ep, const float* __restrict__ al_src,
                               const float* __restrict__ al_dst,
                               float* __restrict__ pbuf, unsigned* __restrict__ m,
                               int* __restrict__ count) {
    int i = blockIdx.x * 256 + threadIdx.x;
    if (i >= NR * EE) return;
    int r = i / EE, ei = i - r * EE;
    const int* e = ep.e[r];
    int sN = e[ei];
    int d = e[EE + ei];
    float l0 = al_src[sN * 2 + 0] + al_dst[d * 2 + 0]; l0 = l0 > 0.f ? l0 : NEG * l0;
    float l1 = al_src[sN * 2 + 1] + al_dst[d * 2 + 1]; l1 = l1 > 0.f ? l1 : NEG * l1;
    pbuf[(size_t)i * 2 + 0] = l0;
    pbuf[(size_t)i * 2 + 1] = l1;
    atomicMax(&m[(r * NN + d) * 2 + 0], f2o(l0));
    atomicMax(&m[(r * NN + d) * 2 + 1], f2o(l1));
    atomicAdd(&count[d], 1);
}

__global__ void s_init_kernel(const float* __restrict__ lself, const unsigned* __restrict__ m,
                              float* __restrict__ s) {
    int i = blockIdx.x * 256 + threadIdx.x;
    if (i >= NR * NN * HH) return;
    int nh = i % (NN * HH);
    s[i] = expf(lself[nh] - o2f(m[i]));
}

__global__ void edge_p_sum(EdgePtrs ep, const unsigned* __restrict__ m,
                           float* __restrict__ pbuf, float* __restrict__ s) {
    int i = blockIdx.x * 256 + threadIdx.x;
    if (i >= NR * EE) return;
    int r = i / EE, ei = i - r * EE;
    int d = ep.e[r][EE + ei];
    float p0 = expf(pbuf[(size_t)i * 2 + 0] - o2f(m[(r * NN + d) * 2 + 0]));
    float p1 = expf(pbuf[(size_t)i * 2 + 1] - o2f(m[(r * NN + d) * 2 + 1]));
    pbuf[(size_t)i * 2 + 0] = p0;
    pbuf[(size_t)i * 2 + 1] = p1;
    atomicAdd(&s[(r * NN + d) * 2 + 0], p0);
    atomicAdd(&s[(r * NN + d) * 2 + 1], p1);
}

__global__ void scan_kernel(const int* __restrict__ count, int* __restrict__ offs,
                            int* __restrict__ cursor) {
    __shared__ int sh[1024];
    __shared__ int carry;
    int tid = threadIdx.x;
    if (tid == 0) carry = 0;
    __syncthreads();
    for (int base = 0; base < NN; base += 1024) {
        int v = (base + tid < NN) ? count[base + tid] : 0;
        sh[tid] = v;
        __syncthreads();
        for (int st = 1; st < 1024; st <<= 1) {
            int t = (tid >= st) ? sh[tid - st] : 0;
            __syncthreads();
            sh[tid] += t;
            __syncthreads();
        }
        int excl = sh[tid] - v + carry;
        if (base + tid < NN) { offs[base + tid] = excl; cursor[base + tid] = excl; }
        __syncthreads();
        if (tid == 0) carry += sh[1023];
        __syncthreads();
    }
    if (tid == 0) offs[NN] = carry;
}

__global__ void scatter_kernel(EdgePtrs ep, const float* __restrict__ pbuf,
                               const float* __restrict__ s, int* __restrict__ cursor,
                               int4* __restrict__ recs) {
    int i = blockIdx.x * 256 + threadIdx.x;
    if (i >= NR * EE) return;
    int r = i / EE, ei = i - r * EE;
    int sN = ep.e[r][ei];
    int d = ep.e[r][EE + ei];
    int slot = atomicAdd(&cursor[d], 1);
    float a0 = pbuf[(size_t)i * 2 + 0] / (s[(r * NN + d) * 2 + 0] + 1e-16f);
    float a1 = pbuf[(size_t)i * 2 + 1] / (s[(r * NN + d) * 2 + 1] + 1e-16f);
    int4 rec;
    rec.x = sN;
    rec.y = __float_as_int(a0);
    rec.z = __float_as_int(a1);
    rec.w = 0;
    recs[slot] = rec;
}

// L1 aggregate: 1024 ch, bf16 in/out, relu. 128 threads x 8 ch.
__global__ void aggregate_l1(const unsigned short* __restrict__ xs, const int4* __restrict__ recs,
                             const int* __restrict__ offs, const float* __restrict__ lself,
                             const unsigned* __restrict__ m, const float* __restrict__ s,
                             const float* __restrict__ bias, unsigned short* __restrict__ out) {
    int n = blockIdx.x;
    int t = threadIdx.x;
    int h = t >> 6;
    float l = lself[n * 2 + h];
    float coef = 0.f;
    for (int r = 0; r < NR; ++r) {
        int idx = (r * NN + n) * 2 + h;
        coef += expf(l - o2f(m[idx])) / (s[idx] + 1e-16f);
    }
    float acc[8], f[8];
    uint4 sv = *(const uint4*)&xs[(size_t)n * 1024 + t * 8];
    unpack8(sv, f);
#pragma unroll
    for (int j = 0; j < 8; ++j) acc[j] = coef * f[j] + 6.f * bias[t * 8 + j];
    int beg = offs[n], end = offs[n + 1];
    int4 rec;
    if (beg < end) rec = recs[beg];
    for (int j = beg; j < end; ++j) {
        int4 cur = rec;
        if (j + 1 < end) rec = recs[j + 1];
        float alpha = h ? __int_as_float(cur.z) : __int_as_float(cur.y);
        uint4 v = *(const uint4*)&xs[(size_t)cur.x * 1024 + t * 8];
        unpack8(v, f);
#pragma unroll
        for (int jj = 0; jj < 8; ++jj) acc[jj] = fmaf(alpha, f[jj], acc[jj]);
    }
#pragma unroll
    for (int j = 0; j < 8; ++j) acc[j] = fmaxf(acc[j], 0.f);
    uint4 o;
    o.x = pack2(acc[0], acc[1]); o.y = pack2(acc[2], acc[3]);
    o.z = pack2(acc[4], acc[5]); o.w = pack2(acc[6], acc[7]);
    *(uint4*)&out[(size_t)n * 1024 + t * 8] = o;
}

// L2 aggregate: 256 ch, bf16 in, fp32 out, no relu. 64 threads x 4 ch.
__global__ void aggregate_l2(const unsigned short* __restrict__ xs, const int4* __restrict__ recs,
                             const int* __restrict__ offs, const float* __restrict__ lself,
                             const unsigned* __restrict__ m, const float* __restrict__ s,
                             const float* __restrict__ bias, float* __restrict__ out) {
    int n = blockIdx.x;
    int t = threadIdx.x;
    int h = t >> 5;
    float l = lself[n * 2 + h];
    float coef = 0.f;
    for (int r = 0; r < NR; ++r) {
        int idx = (r * NN + n) * 2 + h;
        coef += expf(l - o2f(m[idx])) / (s[idx] + 1e-16f);
    }
    float acc[4];
    uint2 sv = *(const uint2*)&xs[(size_t)n * 256 + t * 4];
    float f0 = __uint_as_float(sv.x << 16), f1 = __uint_as_float(sv.x & 0xffff0000u);
    float f2 = __uint_as_float(sv.y << 16), f3 = __uint_as_float(sv.y & 0xffff0000u);
    acc[0] = coef * f0 + 6.f * bias[t * 4 + 0];
    acc[1] = coef * f1 + 6.f * bias[t * 4 + 1];
    acc[2] = coef * f2 + 6.f * bias[t * 4 + 2];
    acc[3] = coef * f3 + 6.f * bias[t * 4 + 3];
    int beg = offs[n], end = offs[n + 1];
    int4 rec;
    if (beg < end) rec = recs[beg];
    for (int j = beg; j < end; ++j) {
        int4 cur = rec;
        if (j + 1 < end) rec = recs[j + 1];
        float alpha = h ? __int_as_float(cur.z) : __int_as_float(cur.y);
        uint2 v = *(const uint2*)&xs[(size_t)cur.x * 256 + t * 4];
        acc[0] = fmaf(alpha, __uint_as_float(v.x << 16), acc[0]);
        acc[1] = fmaf(alpha, __uint_as_float(v.x & 0xffff0000u), acc[1]);
        acc[2] = fmaf(alpha, __uint_as_float(v.y << 16), acc[2]);
        acc[3] = fmaf(alpha, __uint_as_float(v.y & 0xffff0000u), acc[3]);
    }
    float4 o = make_float4(acc[0], acc[1], acc[2], acc[3]);
    *(float4*)&out[(size_t)n * 256 + t * 4] = o;
}

extern "C" void kernel_launch(void* const* d_in, const int* in_sizes, int n_in,
                              void* d_out, int out_size, void* d_ws, size_t ws_size,
                              hipStream_t stream) {
    const float* x = (const float*)d_in[0];
    EdgePtrs ep;
    for (int r = 0; r < NR; ++r) ep.e[r] = (const int*)d_in[1 + r];
    const float* W1s = (const float*)d_in[7];
    const float* a1s = (const float*)d_in[9];
    const float* a1d = (const float*)d_in[10];
    const float* b1  = (const float*)d_in[11];
    const float* W2s = (const float*)d_in[12];
    const float* a2s = (const float*)d_in[14];
    const float* a2d = (const float*)d_in[15];
    const float* b2  = (const float*)d_in[16];
    const float* W1d = (const float*)d_in[8];
    const float* W2d = (const float*)d_in[13];
    float* out = (float*)d_out;

    char* base = (char*)d_ws;
    size_t off = 0;
    auto take = [&](size_t nbytes) -> void* {
        void* p = base + off;
        off = (off + nbytes + 255) & ~(size_t)255;
        return p;
    };
    unsigned short* xb   = (unsigned short*)take((size_t)NN * 512 * 2);
    unsigned short* xs1b = (unsigned short*)take((size_t)NN * 1024 * 2);
    unsigned short* h1b  = (unsigned short*)take((size_t)NN * 1024 * 2);
    unsigned short* xs2b = xs1b;  // reuse (xs1 dead after L1 aggregate)
    unsigned short* Wb   = (unsigned short*)take((size_t)1024 * 512 * 2);
    float* alsrc = (float*)take((size_t)NN * HH * 4);
    float* aldst = (float*)take((size_t)NN * HH * 4);
    float* lself = (float*)take((size_t)NN * HH * 4);
    unsigned* m  = (unsigned*)take((size_t)NR * NN * HH * 4);
    float* s     = (float*)take((size_t)NR * NN * HH * 4);
    float* pbuf  = (float*)take((size_t)NR * EE * HH * 4);
    int* count   = (int*)take((size_t)NN * 4);
    int* offs    = (int*)take((size_t)(NN + 1) * 4);
    int* cursor  = (int*)take((size_t)NN * 4);
    int4* recs   = (int4*)take((size_t)NR * EE * 16);
    float* wts   = (float*)take((size_t)HH * 1024 * 4);
    float* wtd   = (float*)take((size_t)HH * 1024 * 4);

    const int EB = (NR * EE + 255) / 256;
    const int SB = (NR * NN * HH + 255) / 256;

    // ---------------- Layer 1: K=512, C=512, Nout=1024 ----------------
    {
        const int K = 512, C = 512, Nout = 1024;
        f2b_kernel<<<(NN * 512 / 4 + 255) / 256, 256, 0, stream>>>(x, xb, NN * 512);
        f2b_kernel<<<(Nout * K / 4 + 255) / 256, 256, 0, stream>>>(W1s, Wb, Nout * K);
        fold_a_kernel<<<dim3(K / 64, HH), 256, 0, stream>>>(W1s, a1s, wts, C, K);
        fold_a_kernel<<<dim3(K / 64, HH), 256, 0, stream>>>(W1d, a1d, wtd, C, K);
        gemm_nt_mfma<<<dim3(Nout / 128, (NN + 127) / 128), 256, 0, stream>>>(xb, Wb, xs1b, NN, Nout, K);
        al_kernel_b<<<NN, 256, 0, stream>>>(xb, wts, wtd, K, alsrc, aldst, lself, m, count);
        edge_logit_max<<<EB, 256, 0, stream>>>(ep, alsrc, aldst, pbuf, m, count);
        s_init_kernel<<<SB, 256, 0, stream>>>(lself, m, s);
        edge_p_sum<<<EB, 256, 0, stream>>>(ep, m, pbuf, s);
        scan_kernel<<<1, 1024, 0, stream>>>(count, offs, cursor);
        scatter_kernel<<<EB, 256, 0, stream>>>(ep, pbuf, s, cursor, recs);
        aggregate_l1<<<NN, 128, 0, stream>>>(xs1b, recs, offs, lself, m, s, b1, h1b);
    }
    // ---------------- Layer 2: K=1024, C=128, Nout=256 ----------------
    {
        const int K = 1024, C = 128, Nout = 256;
        f2b_kernel<<<(Nout * K / 4 + 255) / 256, 256, 0, stream>>>(W2s, Wb, Nout * K);
        fold_a_kernel<<<dim3(K / 64, HH), 256, 0, stream>>>(W2s, a2s, wts, C, K);
        fold_a_kernel<<<dim3(K / 64, HH), 256, 0, stream>>>(W2d, a2d, wtd, C, K);
        gemm_nt_mfma<<<dim3(Nout / 128, (NN + 127) / 128), 256, 0, stream>>>(h1b, Wb, xs2b, NN, Nout, K);
        al_kernel_b<<<NN, 256, 0, stream>>>(h1b, wts, wtd, K, alsrc, aldst, lself, m, count);
        edge_logit_max<<<EB, 256, 0, stream>>>(ep, alsrc, aldst, pbuf, m, count);
        s_init_kernel<<<SB, 256, 0, stream>>>(lself, m, s);
        edge_p_sum<<<EB, 256, 0, stream>>>(ep, m, pbuf, s);
        scan_kernel<<<1, 1024, 0, stream>>>(count, offs, cursor);
        scatter_kernel<<<EB, 256, 0, stream>>>(ep, pbuf, s, cursor, recs);
        aggregate_l2<<<NN, 64, 0, stream>>>(xs2b, recs, offs, lself, m, s, b2, out);
    }
}

// Round 5
// 749.328 us; speedup vs baseline: 2.3145x; 1.1751x over previous
//
#include <hip/hip_runtime.h>
#include <cstddef>

#define NN 20000
#define EE 100000
#define NR 6
#define HH 2
#define NEG 0.2f
#define NB ((NN + 1023) / 1024)

struct EdgePtrs { const int* e[NR]; };

typedef __attribute__((ext_vector_type(8))) short bf16x8;
typedef __attribute__((ext_vector_type(4))) float f32x4;

__device__ __forceinline__ unsigned f2o(float f) {
    unsigned u = __float_as_uint(f);
    return (u & 0x80000000u) ? ~u : (u | 0x80000000u);
}
__device__ __forceinline__ float o2f(unsigned u) {
    return (u & 0x80000000u) ? __uint_as_float(u & 0x7fffffffu) : __uint_as_float(~u);
}
__device__ __forceinline__ unsigned short rnebf(float f) {
    unsigned u = __float_as_uint(f);
    return (unsigned short)((u + 0x7fffu + ((u >> 16) & 1u)) >> 16);
}
__device__ __forceinline__ float b2f(unsigned short b) {
    return __uint_as_float(((unsigned)b) << 16);
}
__device__ __forceinline__ void unpack8(uint4 v, float* f) {
    f[0] = __uint_as_float(v.x << 16); f[1] = __uint_as_float(v.x & 0xffff0000u);
    f[2] = __uint_as_float(v.y << 16); f[3] = __uint_as_float(v.y & 0xffff0000u);
    f[4] = __uint_as_float(v.z << 16); f[5] = __uint_as_float(v.z & 0xffff0000u);
    f[6] = __uint_as_float(v.w << 16); f[7] = __uint_as_float(v.w & 0xffff0000u);
}
__device__ __forceinline__ unsigned pack2(float a, float b) {
    return (unsigned)rnebf(a) | ((unsigned)rnebf(b) << 16);
}
__device__ __forceinline__ void glld16(unsigned short* lds, const void* g) {
    __builtin_amdgcn_global_load_lds(
        (const __attribute__((address_space(1))) unsigned int*)g,
        (__attribute__((address_space(3))) unsigned int*)lds, 16, 0, 0);
}

// fp32 -> bf16 RNE, 4 elems/thread
__global__ void f2b_kernel(const float* __restrict__ in, unsigned short* __restrict__ out, int n) {
    int i = (blockIdx.x * 256 + threadIdx.x) * 4;
    if (i >= n) return;
    float4 v = *(const float4*)&in[i];
    unsigned short o[4] = {rnebf(v.x), rnebf(v.y), rnebf(v.z), rnebf(v.w)};
    *(uint2*)&out[i] = *(uint2*)o;
}

// wt[h][k] = sum_c a[h,c] * W[h*C+c, k]
__global__ void fold_a_kernel(const float* __restrict__ W, const float* __restrict__ a,
                              float* __restrict__ wt, int C, int K) {
    __shared__ float red[256];
    int h = blockIdx.y;
    int k = blockIdx.x * 64 + (threadIdx.x & 63);
    int cp = threadIdx.x >> 6;
    float acc = 0.f;
    for (int c = cp; c < C; c += 4)
        acc = fmaf(a[h * C + c], W[(size_t)(h * C + c) * K + k], acc);
    red[threadIdx.x] = acc;
    __syncthreads();
    if (cp == 0) {
        acc = red[threadIdx.x] + red[threadIdx.x + 64] +
              red[threadIdx.x + 128] + red[threadIdx.x + 192];
        wt[h * K + k] = acc;
    }
}

// C[M][Nn] = A[M][K] @ B[Nn][K]^T, bf16 in/out, fp32 accum (MFMA 16x16x32)
__global__ __launch_bounds__(256) void gemm_nt_mfma(
    const unsigned short* __restrict__ A, const unsigned short* __restrict__ B,
    unsigned short* __restrict__ C, int M, int Nn, int K) {
    __shared__ unsigned short As[128 * 32];
    __shared__ unsigned short Bs[128 * 32];
    const int tid = threadIdx.x;
    const int lane = tid & 63;
    const int wave = tid >> 6;
    const int wr = wave >> 1, wc = wave & 1;
    const int row0 = blockIdx.y * 128, col0 = blockIdx.x * 128;

    f32x4 acc[4][4];
#pragma unroll
    for (int i = 0; i < 4; ++i)
#pragma unroll
        for (int j = 0; j < 4; ++j) acc[i][j] = (f32x4){0.f, 0.f, 0.f, 0.f};

    const int srow = tid >> 2;
    const int slot = tid & 3;
    const int sw = ((slot ^ (srow & 3)) << 4);
    int ar0 = row0 + srow;        if (ar0 >= M) ar0 = M - 1;
    int ar1 = row0 + srow + 64;   if (ar1 >= M) ar1 = M - 1;
    const int br0 = col0 + srow;
    const int br1 = col0 + srow + 64;

    const int q = lane >> 4;
    for (int k0 = 0; k0 < K; k0 += 32) {
        glld16(As + tid * 8,        (const char*)A + ((size_t)ar0 * K + k0) * 2 + sw);
        glld16(As + tid * 8 + 2048, (const char*)A + ((size_t)ar1 * K + k0) * 2 + sw);
        glld16(Bs + tid * 8,        (const char*)B + ((size_t)br0 * K + k0) * 2 + sw);
        glld16(Bs + tid * 8 + 2048, (const char*)B + ((size_t)br1 * K + k0) * 2 + sw);
        __syncthreads();
        bf16x8 af[4], bfr[4];
#pragma unroll
        for (int m = 0; m < 4; ++m) {
            int r = wr * 64 + m * 16 + (lane & 15);
            af[m] = *(const bf16x8*)&As[r * 32 + ((q ^ (r & 3)) << 3)];
        }
#pragma unroll
        for (int nI = 0; nI < 4; ++nI) {
            int c = wc * 64 + nI * 16 + (lane & 15);
            bfr[nI] = *(const bf16x8*)&Bs[c * 32 + ((q ^ (c & 3)) << 3)];
        }
#pragma unroll
        for (int m = 0; m < 4; ++m)
#pragma unroll
            for (int nI = 0; nI < 4; ++nI)
                acc[m][nI] = __builtin_amdgcn_mfma_f32_16x16x32_bf16(af[m], bfr[nI], acc[m][nI], 0, 0, 0);
        __syncthreads();
    }
    const int crow = (lane >> 4) * 4;
    const int ccol = lane & 15;
#pragma unroll
    for (int m = 0; m < 4; ++m)
#pragma unroll
        for (int nI = 0; nI < 4; ++nI)
#pragma unroll
            for (int j = 0; j < 4; ++j) {
                int r = row0 + wr * 64 + m * 16 + crow + j;
                int c = col0 + wc * 64 + nI * 16 + ccol;
                if (r < M) C[(size_t)r * Nn + c] = rnebf(acc[m][nI][j]);
            }
}

// wave-per-node: al_src/al_dst, l_self, init m, zero count. block = 4 waves.
__global__ void al_kernel_w(const unsigned short* __restrict__ x, const float* __restrict__ wts,
                            const float* __restrict__ wtd, int K,
                            float* __restrict__ al_src, float* __restrict__ al_dst,
                            float* __restrict__ lself, unsigned* __restrict__ m,
                            int* __restrict__ count) {
    int lane = threadIdx.x & 63;
    int n = blockIdx.x * 4 + (threadIdx.x >> 6);
    if (n >= NN) return;
    float s0 = 0.f, s1 = 0.f, d0 = 0.f, d1 = 0.f;
    for (int k0 = 0; k0 < K; k0 += 512) {
        int k = k0 + lane * 8;
        uint4 xv = *(const uint4*)&x[(size_t)n * K + k];
        float xf[8];
        unpack8(xv, xf);
        float4 wsa = *(const float4*)&wts[k],     wsb = *(const float4*)&wts[k + 4];
        float4 wsc = *(const float4*)&wts[K + k], wsd = *(const float4*)&wts[K + k + 4];
        float4 wda = *(const float4*)&wtd[k],     wdb = *(const float4*)&wtd[k + 4];
        float4 wdc = *(const float4*)&wtd[K + k], wdd = *(const float4*)&wtd[K + k + 4];
        s0 = fmaf(xf[0], wsa.x, s0); s0 = fmaf(xf[1], wsa.y, s0);
        s0 = fmaf(xf[2], wsa.z, s0); s0 = fmaf(xf[3], wsa.w, s0);
        s0 = fmaf(xf[4], wsb.x, s0); s0 = fmaf(xf[5], wsb.y, s0);
        s0 = fmaf(xf[6], wsb.z, s0); s0 = fmaf(xf[7], wsb.w, s0);
        s1 = fmaf(xf[0], wsc.x, s1); s1 = fmaf(xf[1], wsc.y, s1);
        s1 = fmaf(xf[2], wsc.z, s1); s1 = fmaf(xf[3], wsc.w, s1);
        s1 = fmaf(xf[4], wsd.x, s1); s1 = fmaf(xf[5], wsd.y, s1);
        s1 = fmaf(xf[6], wsd.z, s1); s1 = fmaf(xf[7], wsd.w, s1);
        d0 = fmaf(xf[0], wda.x, d0); d0 = fmaf(xf[1], wda.y, d0);
        d0 = fmaf(xf[2], wda.z, d0); d0 = fmaf(xf[3], wda.w, d0);
        d0 = fmaf(xf[4], wdb.x, d0); d0 = fmaf(xf[5], wdb.y, d0);
        d0 = fmaf(xf[6], wdb.z, d0); d0 = fmaf(xf[7], wdb.w, d0);
        d1 = fmaf(xf[0], wdc.x, d1); d1 = fmaf(xf[1], wdc.y, d1);
        d1 = fmaf(xf[2], wdc.z, d1); d1 = fmaf(xf[3], wdc.w, d1);
        d1 = fmaf(xf[4], wdd.x, d1); d1 = fmaf(xf[5], wdd.y, d1);
        d1 = fmaf(xf[6], wdd.z, d1); d1 = fmaf(xf[7], wdd.w, d1);
    }
    for (int o = 32; o > 0; o >>= 1) {
        s0 += __shfl_down(s0, o); s1 += __shfl_down(s1, o);
        d0 += __shfl_down(d0, o); d1 += __shfl_down(d1, o);
    }
    if (lane == 0) {
        float as0 = s0, as1 = s1, ad0 = d0, ad1 = d1;
        al_src[n * 2 + 0] = as0; al_src[n * 2 + 1] = as1;
        al_dst[n * 2 + 0] = ad0; al_dst[n * 2 + 1] = ad1;
        float l0 = as0 + ad0; l0 = l0 > 0.f ? l0 : NEG * l0;
        float l1 = as1 + ad1; l1 = l1 > 0.f ? l1 : NEG * l1;
        lself[n * 2 + 0] = l0; lself[n * 2 + 1] = l1;
        unsigned e0 = f2o(l0), e1 = f2o(l1);
        for (int r = 0; r < NR; ++r) {
            m[(r * NN + n) * 2 + 0] = e0;
            m[(r * NN + n) * 2 + 1] = e1;
        }
        count[n] = 0;
    }
}

__global__ void count_kernel(EdgePtrs ep, int* __restrict__ count) {
    int i = blockIdx.x * 256 + threadIdx.x;
    if (i >= NR * EE) return;
    int r = i / EE, ei = i - r * EE;
    atomicAdd(&count[ep.e[r][EE + ei]], 1);
}

__global__ void edge_logit_max(EdgePtrs ep, const float* __restrict__ al_src,
                               const float* __restrict__ al_dst,
                               float* __restrict__ pbuf, unsigned* __restrict__ m) {
    int i = blockIdx.x * 256 + threadIdx.x;
    if (i >= NR * EE) return;
    int r = i / EE, ei = i - r * EE;
    const int* e = ep.e[r];
    int sN = e[ei];
    int d = e[EE + ei];
    float l0 = al_src[sN * 2 + 0] + al_dst[d * 2 + 0]; l0 = l0 > 0.f ? l0 : NEG * l0;
    float l1 = al_src[sN * 2 + 1] + al_dst[d * 2 + 1]; l1 = l1 > 0.f ? l1 : NEG * l1;
    pbuf[(size_t)i * 2 + 0] = l0;
    pbuf[(size_t)i * 2 + 1] = l1;
    atomicMax(&m[(r * NN + d) * 2 + 0], f2o(l0));
    atomicMax(&m[(r * NN + d) * 2 + 1], f2o(l1));
}

__global__ void s_init_kernel(const float* __restrict__ lself, const unsigned* __restrict__ m,
                              float* __restrict__ s) {
    int i = blockIdx.x * 256 + threadIdx.x;
    if (i >= NR * NN * HH) return;
    int nh = i % (NN * HH);
    s[i] = expf(lself[nh] - o2f(m[i]));
}

__global__ void edge_p_sum(EdgePtrs ep, const unsigned* __restrict__ m,
                           float* __restrict__ pbuf, float* __restrict__ s) {
    int i = blockIdx.x * 256 + threadIdx.x;
    if (i >= NR * EE) return;
    int r = i / EE, ei = i - r * EE;
    int d = ep.e[r][EE + ei];
    float p0 = expf(pbuf[(size_t)i * 2 + 0] - o2f(m[(r * NN + d) * 2 + 0]));
    float p1 = expf(pbuf[(size_t)i * 2 + 1] - o2f(m[(r * NN + d) * 2 + 1]));
    pbuf[(size_t)i * 2 + 0] = p0;
    pbuf[(size_t)i * 2 + 1] = p1;
    atomicAdd(&s[(r * NN + d) * 2 + 0], p0);
    atomicAdd(&s[(r * NN + d) * 2 + 1], p1);
}

// --- 3-stage parallel exclusive scan of count[NN] -> offs, cursor ---
__global__ void block_sum(const int* __restrict__ count, int* __restrict__ bsum) {
    int base = blockIdx.x * 1024;
    int tid = threadIdx.x;
    int s = 0;
    for (int i = tid; i < 1024; i += 256) {
        int idx = base + i;
        s += (idx < NN) ? count[idx] : 0;
    }
    for (int o = 32; o > 0; o >>= 1) s += __shfl_down(s, o);
    __shared__ int ws[4];
    if ((tid & 63) == 0) ws[tid >> 6] = s;
    __syncthreads();
    if (tid == 0) bsum[blockIdx.x] = ws[0] + ws[1] + ws[2] + ws[3];
}

__global__ void scan_small(const int* __restrict__ bsum, int* __restrict__ bbase,
                           int* __restrict__ offs) {
    if (threadIdx.x == 0) {
        int run = 0;
        for (int i = 0; i < NB; ++i) { bbase[i] = run; run += bsum[i]; }
        offs[NN] = run;
    }
}

__global__ void scan_blocks(const int* __restrict__ count, const int* __restrict__ bbase,
                            int* __restrict__ offs, int* __restrict__ cursor) {
    __shared__ int wsum[16];
    __shared__ int wbase[16];
    int tid = threadIdx.x;
    int lane = tid & 63;
    int wid = tid >> 6;
    int idx = blockIdx.x * 1024 + tid;
    int v = (idx < NN) ? count[idx] : 0;
    int xv = v;
    for (int d = 1; d < 64; d <<= 1) {
        int t = __shfl_up(xv, d);
        if (lane >= d) xv += t;
    }
    if (lane == 63) wsum[wid] = xv;
    __syncthreads();
    if (wid == 0 && lane < 16) {
        int wv = wsum[lane];
        int wx = wv;
        for (int d = 1; d < 16; d <<= 1) {
            int t = __shfl_up(wx, d);
            if (lane >= d) wx += t;
        }
        wbase[lane] = wx - wv;
    }
    __syncthreads();
    int excl = xv - v + wbase[wid] + bbase[blockIdx.x];
    if (idx < NN) { offs[idx] = excl; cursor[idx] = excl; }
}

__global__ void copy_cursor(const int* __restrict__ offs, int* __restrict__ cursor) {
    int i = blockIdx.x * 256 + threadIdx.x;
    if (i < NN) cursor[i] = offs[i];
}

__global__ void scatter_kernel(EdgePtrs ep, const float* __restrict__ pbuf,
                               const float* __restrict__ s, int* __restrict__ cursor,
                               int4* __restrict__ recs) {
    int i = blockIdx.x * 256 + threadIdx.x;
    if (i >= NR * EE) return;
    int r = i / EE, ei = i - r * EE;
    int sN = ep.e[r][ei];
    int d = ep.e[r][EE + ei];
    int slot = atomicAdd(&cursor[d], 1);
    float a0 = pbuf[(size_t)i * 2 + 0] / (s[(r * NN + d) * 2 + 0] + 1e-16f);
    float a1 = pbuf[(size_t)i * 2 + 1] / (s[(r * NN + d) * 2 + 1] + 1e-16f);
    int4 rec;
    rec.x = sN;
    rec.y = __float_as_int(a0);
    rec.z = __float_as_int(a1);
    rec.w = 0;
    recs[slot] = rec;
}

// L1 aggregate: 1024 ch, bf16 in/out, relu. 128 thr x 8 ch, 4-way edge ILP.
__global__ void aggregate_l1(const unsigned short* __restrict__ xs, const int4* __restrict__ recs,
                             const int* __restrict__ offs, const float* __restrict__ lself,
                             const unsigned* __restrict__ m, const float* __restrict__ s,
                             const float* __restrict__ bias, unsigned short* __restrict__ out) {
    int n = blockIdx.x;
    int t = threadIdx.x;
    int h = t >> 6;
    float l = lself[n * 2 + h];
    float coef = 0.f;
    for (int r = 0; r < NR; ++r) {
        int idx = (r * NN + n) * 2 + h;
        coef += expf(l - o2f(m[idx])) / (s[idx] + 1e-16f);
    }
    float a0[8], a1[8], a2[8], a3[8], f[8];
    uint4 sv = *(const uint4*)&xs[(size_t)n * 1024 + t * 8];
    unpack8(sv, f);
#pragma unroll
    for (int j = 0; j < 8; ++j) {
        a0[j] = coef * f[j] + 6.f * bias[t * 8 + j];
        a1[j] = 0.f; a2[j] = 0.f; a3[j] = 0.f;
    }
    int beg = offs[n], end = offs[n + 1];
    int j = beg;
    for (; j + 3 < end; j += 4) {
        int4 r0 = recs[j], r1 = recs[j + 1], r2 = recs[j + 2], r3 = recs[j + 3];
        uint4 v0 = *(const uint4*)&xs[(size_t)r0.x * 1024 + t * 8];
        uint4 v1 = *(const uint4*)&xs[(size_t)r1.x * 1024 + t * 8];
        uint4 v2 = *(const uint4*)&xs[(size_t)r2.x * 1024 + t * 8];
        uint4 v3 = *(const uint4*)&xs[(size_t)r3.x * 1024 + t * 8];
        float al0 = h ? __int_as_float(r0.z) : __int_as_float(r0.y);
        float al1 = h ? __int_as_float(r1.z) : __int_as_float(r1.y);
        float al2 = h ? __int_as_float(r2.z) : __int_as_float(r2.y);
        float al3 = h ? __int_as_float(r3.z) : __int_as_float(r3.y);
        unpack8(v0, f);
#pragma unroll
        for (int q = 0; q < 8; ++q) a0[q] = fmaf(al0, f[q], a0[q]);
        unpack8(v1, f);
#pragma unroll
        for (int q = 0; q < 8; ++q) a1[q] = fmaf(al1, f[q], a1[q]);
        unpack8(v2, f);
#pragma unroll
        for (int q = 0; q < 8; ++q) a2[q] = fmaf(al2, f[q], a2[q]);
        unpack8(v3, f);
#pragma unroll
        for (int q = 0; q < 8; ++q) a3[q] = fmaf(al3, f[q], a3[q]);
    }
    for (; j < end; ++j) {
        int4 r0 = recs[j];
        uint4 v0 = *(const uint4*)&xs[(size_t)r0.x * 1024 + t * 8];
        float al0 = h ? __int_as_float(r0.z) : __int_as_float(r0.y);
        unpack8(v0, f);
#pragma unroll
        for (int q = 0; q < 8; ++q) a0[q] = fmaf(al0, f[q], a0[q]);
    }
    uint4 o;
    float r0_ = fmaxf(a0[0] + a1[0] + a2[0] + a3[0], 0.f);
    float r1_ = fmaxf(a0[1] + a1[1] + a2[1] + a3[1], 0.f);
    float r2_ = fmaxf(a0[2] + a1[2] + a2[2] + a3[2], 0.f);
    float r3_ = fmaxf(a0[3] + a1[3] + a2[3] + a3[3], 0.f);
    float r4_ = fmaxf(a0[4] + a1[4] + a2[4] + a3[4], 0.f);
    float r5_ = fmaxf(a0[5] + a1[5] + a2[5] + a3[5], 0.f);
    float r6_ = fmaxf(a0[6] + a1[6] + a2[6] + a3[6], 0.f);
    float r7_ = fmaxf(a0[7] + a1[7] + a2[7] + a3[7], 0.f);
    o.x = pack2(r0_, r1_); o.y = pack2(r2_, r3_);
    o.z = pack2(r4_, r5_); o.w = pack2(r6_, r7_);
    *(uint4*)&out[(size_t)n * 1024 + t * 8] = o;
}

// L2 aggregate: 256 ch, bf16 in, fp32 out. 64 thr x 4 ch, 4-way edge ILP.
__global__ void aggregate_l2(const unsigned short* __restrict__ xs, const int4* __restrict__ recs,
                             const int* __restrict__ offs, const float* __restrict__ lself,
                             const unsigned* __restrict__ m, const float* __restrict__ s,
                             const float* __restrict__ bias, float* __restrict__ out) {
    int n = blockIdx.x;
    int t = threadIdx.x;
    int h = t >> 5;
    float l = lself[n * 2 + h];
    float coef = 0.f;
    for (int r = 0; r < NR; ++r) {
        int idx = (r * NN + n) * 2 + h;
        coef += expf(l - o2f(m[idx])) / (s[idx] + 1e-16f);
    }
    float a0[4], a1[4], a2[4], a3[4];
    uint2 sv = *(const uint2*)&xs[(size_t)n * 256 + t * 4];
    a0[0] = coef * __uint_as_float(sv.x << 16)          + 6.f * bias[t * 4 + 0];
    a0[1] = coef * __uint_as_float(sv.x & 0xffff0000u)  + 6.f * bias[t * 4 + 1];
    a0[2] = coef * __uint_as_float(sv.y << 16)          + 6.f * bias[t * 4 + 2];
    a0[3] = coef * __uint_as_float(sv.y & 0xffff0000u)  + 6.f * bias[t * 4 + 3];
#pragma unroll
    for (int q = 0; q < 4; ++q) { a1[q] = 0.f; a2[q] = 0.f; a3[q] = 0.f; }
    int beg = offs[n], end = offs[n + 1];
    int j = beg;
    for (; j + 3 < end; j += 4) {
        int4 r0 = recs[j], r1 = recs[j + 1], r2 = recs[j + 2], r3 = recs[j + 3];
        uint2 v0 = *(const uint2*)&xs[(size_t)r0.x * 256 + t * 4];
        uint2 v1 = *(const uint2*)&xs[(size_t)r1.x * 256 + t * 4];
        uint2 v2 = *(const uint2*)&xs[(size_t)r2.x * 256 + t * 4];
        uint2 v3 = *(const uint2*)&xs[(size_t)r3.x * 256 + t * 4];
        float al0 = h ? __int_as_float(r0.z) : __int_as_float(r0.y);
        float al1 = h ? __int_as_float(r1.z) : __int_as_float(r1.y);
        float al2 = h ? __int_as_float(r2.z) : __int_as_float(r2.y);
        float al3 = h ? __int_as_float(r3.z) : __int_as_float(r3.y);
        a0[0] = fmaf(al0, __uint_as_float(v0.x << 16), a0[0]);
        a0[1] = fmaf(al0, __uint_as_float(v0.x & 0xffff0000u), a0[1]);
        a0[2] = fmaf(al0, __uint_as_float(v0.y << 16), a0[2]);
        a0[3] = fmaf(al0, __uint_as_float(v0.y & 0xffff0000u), a0[3]);
        a1[0] = fmaf(al1, __uint_as_float(v1.x << 16), a1[0]);
        a1[1] = fmaf(al1, __uint_as_float(v1.x & 0xffff0000u), a1[1]);
        a1[2] = fmaf(al1, __uint_as_float(v1.y << 16), a1[2]);
        a1[3] = fmaf(al1, __uint_as_float(v1.y & 0xffff0000u), a1[3]);
        a2[0] = fmaf(al2, __uint_as_float(v2.x << 16), a2[0]);
        a2[1] = fmaf(al2, __uint_as_float(v2.x & 0xffff0000u), a2[1]);
        a2[2] = fmaf(al2, __uint_as_float(v2.y << 16), a2[2]);
        a2[3] = fmaf(al2, __uint_as_float(v2.y & 0xffff0000u), a2[3]);
        a3[0] = fmaf(al3, __uint_as_float(v3.x << 16), a3[0]);
        a3[1] = fmaf(al3, __uint_as_float(v3.x & 0xffff0000u), a3[1]);
        a3[2] = fmaf(al3, __uint_as_float(v3.y << 16), a3[2]);
        a3[3] = fmaf(al3, __uint_as_float(v3.y & 0xffff0000u), a3[3]);
    }
    for (; j < end; ++j) {
        int4 r0 = recs[j];
        uint2 v0 = *(const uint2*)&xs[(size_t)r0.x * 256 + t * 4];
        float al0 = h ? __int_as_float(r0.z) : __int_as_float(r0.y);
        a0[0] = fmaf(al0, __uint_as_float(v0.x << 16), a0[0]);
        a0[1] = fmaf(al0, __uint_as_float(v0.x & 0xffff0000u), a0[1]);
        a0[2] = fmaf(al0, __uint_as_float(v0.y << 16), a0[2]);
        a0[3] = fmaf(al0, __uint_as_float(v0.y & 0xffff0000u), a0[3]);
    }
    float4 o = make_float4(a0[0] + a1[0] + a2[0] + a3[0],
                           a0[1] + a1[1] + a2[1] + a3[1],
                           a0[2] + a1[2] + a2[2] + a3[2],
                           a0[3] + a1[3] + a2[3] + a3[3]);
    *(float4*)&out[(size_t)n * 256 + t * 4] = o;
}

extern "C" void kernel_launch(void* const* d_in, const int* in_sizes, int n_in,
                              void* d_out, int out_size, void* d_ws, size_t ws_size,
                              hipStream_t stream) {
    const float* x = (const float*)d_in[0];
    EdgePtrs ep;
    for (int r = 0; r < NR; ++r) ep.e[r] = (const int*)d_in[1 + r];
    const float* W1s = (const float*)d_in[7];
    const float* W1d = (const float*)d_in[8];
    const float* a1s = (const float*)d_in[9];
    const float* a1d = (const float*)d_in[10];
    const float* b1  = (const float*)d_in[11];
    const float* W2s = (const float*)d_in[12];
    const float* W2d = (const float*)d_in[13];
    const float* a2s = (const float*)d_in[14];
    const float* a2d = (const float*)d_in[15];
    const float* b2  = (const float*)d_in[16];
    float* out = (float*)d_out;

    char* base = (char*)d_ws;
    size_t off = 0;
    auto take = [&](size_t nbytes) -> void* {
        void* p = base + off;
        off = (off + nbytes + 255) & ~(size_t)255;
        return p;
    };
    unsigned short* xb   = (unsigned short*)take((size_t)NN * 512 * 2);
    unsigned short* xs1b = (unsigned short*)take((size_t)NN * 1024 * 2);
    unsigned short* h1b  = (unsigned short*)take((size_t)NN * 1024 * 2);
    unsigned short* xs2b = xs1b;  // reuse (xs1 dead after L1 aggregate)
    unsigned short* Wb   = (unsigned short*)take((size_t)1024 * 512 * 2);
    float* alsrc = (float*)take((size_t)NN * HH * 4);
    float* aldst = (float*)take((size_t)NN * HH * 4);
    float* lself = (float*)take((size_t)NN * HH * 4);
    unsigned* m  = (unsigned*)take((size_t)NR * NN * HH * 4);
    float* s     = (float*)take((size_t)NR * NN * HH * 4);
    float* pbuf  = (float*)take((size_t)NR * EE * HH * 4);
    int* count   = (int*)take((size_t)NN * 4);
    int* offs    = (int*)take((size_t)(NN + 1) * 4);
    int* cursor  = (int*)take((size_t)NN * 4);
    int4* recs   = (int4*)take((size_t)NR * EE * 16);
    float* wts   = (float*)take((size_t)HH * 1024 * 4);
    float* wtd   = (float*)take((size_t)HH * 1024 * 4);
    int* bsum    = (int*)take((size_t)NB * 4);
    int* bbase   = (int*)take((size_t)NB * 4);

    const int EB = (NR * EE + 255) / 256;
    const int SB = (NR * NN * HH + 255) / 256;

    // ---------------- Layer 1: K=512, C=512, Nout=1024 ----------------
    {
        const int K = 512, C = 512, Nout = 1024;
        f2b_kernel<<<(NN * 512 / 4 + 255) / 256, 256, 0, stream>>>(x, xb, NN * 512);
        f2b_kernel<<<(Nout * K / 4 + 255) / 256, 256, 0, stream>>>(W1s, Wb, Nout * K);
        fold_a_kernel<<<dim3(K / 64, HH), 256, 0, stream>>>(W1s, a1s, wts, C, K);
        fold_a_kernel<<<dim3(K / 64, HH), 256, 0, stream>>>(W1d, a1d, wtd, C, K);
        gemm_nt_mfma<<<dim3(Nout / 128, (NN + 127) / 128), 256, 0, stream>>>(xb, Wb, xs1b, NN, Nout, K);
        al_kernel_w<<<(NN + 3) / 4, 256, 0, stream>>>(xb, wts, wtd, K, alsrc, aldst, lself, m, count);
        count_kernel<<<EB, 256, 0, stream>>>(ep, count);
        edge_logit_max<<<EB, 256, 0, stream>>>(ep, alsrc, aldst, pbuf, m);
        s_init_kernel<<<SB, 256, 0, stream>>>(lself, m, s);
        edge_p_sum<<<EB, 256, 0, stream>>>(ep, m, pbuf, s);
        block_sum<<<NB, 256, 0, stream>>>(count, bsum);
        scan_small<<<1, 64, 0, stream>>>(bsum, bbase, offs);
        scan_blocks<<<NB, 1024, 0, stream>>>(count, bbase, offs, cursor);
        scatter_kernel<<<EB, 256, 0, stream>>>(ep, pbuf, s, cursor, recs);
        aggregate_l1<<<NN, 128, 0, stream>>>(xs1b, recs, offs, lself, m, s, b1, h1b);
    }
    // ---------------- Layer 2: K=1024, C=128, Nout=256 ----------------
    {
        const int K = 1024, C = 128, Nout = 256;
        f2b_kernel<<<(Nout * K / 4 + 255) / 256, 256, 0, stream>>>(W2s, Wb, Nout * K);
        fold_a_kernel<<<dim3(K / 64, HH), 256, 0, stream>>>(W2s, a2s, wts, C, K);
        fold_a_kernel<<<dim3(K / 64, HH), 256, 0, stream>>>(W2d, a2d, wtd, C, K);
        gemm_nt_mfma<<<dim3(Nout / 128, (NN + 127) / 128), 256, 0, stream>>>(h1b, Wb, xs2b, NN, Nout, K);
        al_kernel_w<<<(NN + 3) / 4, 256, 0, stream>>>(h1b, wts, wtd, K, alsrc, aldst, lself, m, count);
        edge_logit_max<<<EB, 256, 0, stream>>>(ep, alsrc, aldst, pbuf, m);
        s_init_kernel<<<SB, 256, 0, stream>>>(lself, m, s);
        edge_p_sum<<<EB, 256, 0, stream>>>(ep, m, pbuf, s);
        copy_cursor<<<(NN + 255) / 256, 256, 0, stream>>>(offs, cursor);
        scatter_kernel<<<EB, 256, 0, stream>>>(ep, pbuf, s, cursor, recs);
        aggregate_l2<<<NN, 64, 0, stream>>>(xs2b, recs, offs, lself, m, s, b2, out);
    }
}

// Round 6
// 627.903 us; speedup vs baseline: 2.7621x; 1.1934x over previous
//
#include <hip/hip_runtime.h>
#include <cstddef>

#define NN 20000
#define EE 100000
#define NR 6
#define HH 2
#define NEG 0.2f
#define NB ((NN + 1023) / 1024)

struct EdgePtrs { const int* e[NR]; };

typedef __attribute__((ext_vector_type(8))) short bf16x8;
typedef __attribute__((ext_vector_type(4))) float f32x4;

__device__ __forceinline__ unsigned short rnebf(float f) {
    unsigned u = __float_as_uint(f);
    return (unsigned short)((u + 0x7fffu + ((u >> 16) & 1u)) >> 16);
}
__device__ __forceinline__ void unpack8(uint4 v, float* f) {
    f[0] = __uint_as_float(v.x << 16); f[1] = __uint_as_float(v.x & 0xffff0000u);
    f[2] = __uint_as_float(v.y << 16); f[3] = __uint_as_float(v.y & 0xffff0000u);
    f[4] = __uint_as_float(v.z << 16); f[5] = __uint_as_float(v.z & 0xffff0000u);
    f[6] = __uint_as_float(v.w << 16); f[7] = __uint_as_float(v.w & 0xffff0000u);
}
__device__ __forceinline__ unsigned pack2(float a, float b) {
    return (unsigned)rnebf(a) | ((unsigned)rnebf(b) << 16);
}
__device__ __forceinline__ void glld16(unsigned short* lds, const void* g) {
    __builtin_amdgcn_global_load_lds(
        (const __attribute__((address_space(1))) unsigned int*)g,
        (__attribute__((address_space(3))) unsigned int*)lds, 16, 0, 0);
}

// fp32 -> bf16 RNE, 4 elems/thread
__global__ void f2b_kernel(const float* __restrict__ in, unsigned short* __restrict__ out, int n) {
    int i = (blockIdx.x * 256 + threadIdx.x) * 4;
    if (i >= n) return;
    float4 v = *(const float4*)&in[i];
    unsigned short o[4] = {rnebf(v.x), rnebf(v.y), rnebf(v.z), rnebf(v.w)};
    *(uint2*)&out[i] = *(uint2*)o;
}

// wt[h][k] = sum_c a[h,c] * W[h*C+c, k]
__global__ void fold_a_kernel(const float* __restrict__ W, const float* __restrict__ a,
                              float* __restrict__ wt, int C, int K) {
    __shared__ float red[256];
    int h = blockIdx.y;
    int k = blockIdx.x * 64 + (threadIdx.x & 63);
    int cp = threadIdx.x >> 6;
    float acc = 0.f;
    for (int c = cp; c < C; c += 4)
        acc = fmaf(a[h * C + c], W[(size_t)(h * C + c) * K + k], acc);
    red[threadIdx.x] = acc;
    __syncthreads();
    if (cp == 0) {
        acc = red[threadIdx.x] + red[threadIdx.x + 64] +
              red[threadIdx.x + 128] + red[threadIdx.x + 192];
        wt[h * K + k] = acc;
    }
}

// C[M][Nn] = A[M][K] @ B[Nn][K]^T, bf16 in/out, fp32 accum (MFMA 16x16x32)
__global__ __launch_bounds__(256) void gemm_nt_mfma(
    const unsigned short* __restrict__ A, const unsigned short* __restrict__ B,
    unsigned short* __restrict__ C, int M, int Nn, int K) {
    __shared__ unsigned short As[128 * 32];
    __shared__ unsigned short Bs[128 * 32];
    const int tid = threadIdx.x;
    const int lane = tid & 63;
    const int wave = tid >> 6;
    const int wr = wave >> 1, wc = wave & 1;
    const int row0 = blockIdx.y * 128, col0 = blockIdx.x * 128;

    f32x4 acc[4][4];
#pragma unroll
    for (int i = 0; i < 4; ++i)
#pragma unroll
        for (int j = 0; j < 4; ++j) acc[i][j] = (f32x4){0.f, 0.f, 0.f, 0.f};

    const int srow = tid >> 2;
    const int slot = tid & 3;
    const int sw = ((slot ^ (srow & 3)) << 4);
    int ar0 = row0 + srow;        if (ar0 >= M) ar0 = M - 1;
    int ar1 = row0 + srow + 64;   if (ar1 >= M) ar1 = M - 1;
    const int br0 = col0 + srow;
    const int br1 = col0 + srow + 64;

    const int q = lane >> 4;
    for (int k0 = 0; k0 < K; k0 += 32) {
        glld16(As + tid * 8,        (const char*)A + ((size_t)ar0 * K + k0) * 2 + sw);
        glld16(As + tid * 8 + 2048, (const char*)A + ((size_t)ar1 * K + k0) * 2 + sw);
        glld16(Bs + tid * 8,        (const char*)B + ((size_t)br0 * K + k0) * 2 + sw);
        glld16(Bs + tid * 8 + 2048, (const char*)B + ((size_t)br1 * K + k0) * 2 + sw);
        __syncthreads();
        bf16x8 af[4], bfr[4];
#pragma unroll
        for (int m = 0; m < 4; ++m) {
            int r = wr * 64 + m * 16 + (lane & 15);
            af[m] = *(const bf16x8*)&As[r * 32 + ((q ^ (r & 3)) << 3)];
        }
#pragma unroll
        for (int nI = 0; nI < 4; ++nI) {
            int c = wc * 64 + nI * 16 + (lane & 15);
            bfr[nI] = *(const bf16x8*)&Bs[c * 32 + ((q ^ (c & 3)) << 3)];
        }
#pragma unroll
        for (int m = 0; m < 4; ++m)
#pragma unroll
            for (int nI = 0; nI < 4; ++nI)
                acc[m][nI] = __builtin_amdgcn_mfma_f32_16x16x32_bf16(af[m], bfr[nI], acc[m][nI], 0, 0, 0);
        __syncthreads();
    }
    const int crow = (lane >> 4) * 4;
    const int ccol = lane & 15;
#pragma unroll
    for (int m = 0; m < 4; ++m)
#pragma unroll
        for (int nI = 0; nI < 4; ++nI)
#pragma unroll
            for (int j = 0; j < 4; ++j) {
                int r = row0 + wr * 64 + m * 16 + crow + j;
                int c = col0 + wc * 64 + nI * 16 + ccol;
                if (r < M) C[(size_t)r * Nn + c] = rnebf(acc[m][nI][j]);
            }
}

// wave-per-node: al_src/al_dst, lself, s[r][n][h] = exp(l_self), count=0.
__global__ void al_kernel_w(const unsigned short* __restrict__ x, const float* __restrict__ wts,
                            const float* __restrict__ wtd, int K,
                            float* __restrict__ al_src, float* __restrict__ al_dst,
                            float* __restrict__ lself, float* __restrict__ s,
                            int* __restrict__ count) {
    int lane = threadIdx.x & 63;
    int n = blockIdx.x * 4 + (threadIdx.x >> 6);
    if (n >= NN) return;
    float s0 = 0.f, s1 = 0.f, d0 = 0.f, d1 = 0.f;
    for (int k0 = 0; k0 < K; k0 += 512) {
        int k = k0 + lane * 8;
        uint4 xv = *(const uint4*)&x[(size_t)n * K + k];
        float xf[8];
        unpack8(xv, xf);
        float4 wsa = *(const float4*)&wts[k],     wsb = *(const float4*)&wts[k + 4];
        float4 wsc = *(const float4*)&wts[K + k], wsd = *(const float4*)&wts[K + k + 4];
        float4 wda = *(const float4*)&wtd[k],     wdb = *(const float4*)&wtd[k + 4];
        float4 wdc = *(const float4*)&wtd[K + k], wdd = *(const float4*)&wtd[K + k + 4];
        s0 = fmaf(xf[0], wsa.x, s0); s0 = fmaf(xf[1], wsa.y, s0);
        s0 = fmaf(xf[2], wsa.z, s0); s0 = fmaf(xf[3], wsa.w, s0);
        s0 = fmaf(xf[4], wsb.x, s0); s0 = fmaf(xf[5], wsb.y, s0);
        s0 = fmaf(xf[6], wsb.z, s0); s0 = fmaf(xf[7], wsb.w, s0);
        s1 = fmaf(xf[0], wsc.x, s1); s1 = fmaf(xf[1], wsc.y, s1);
        s1 = fmaf(xf[2], wsc.z, s1); s1 = fmaf(xf[3], wsc.w, s1);
        s1 = fmaf(xf[4], wsd.x, s1); s1 = fmaf(xf[5], wsd.y, s1);
        s1 = fmaf(xf[6], wsd.z, s1); s1 = fmaf(xf[7], wsd.w, s1);
        d0 = fmaf(xf[0], wda.x, d0); d0 = fmaf(xf[1], wda.y, d0);
        d0 = fmaf(xf[2], wda.z, d0); d0 = fmaf(xf[3], wda.w, d0);
        d0 = fmaf(xf[4], wdb.x, d0); d0 = fmaf(xf[5], wdb.y, d0);
        d0 = fmaf(xf[6], wdb.z, d0); d0 = fmaf(xf[7], wdb.w, d0);
        d1 = fmaf(xf[0], wdc.x, d1); d1 = fmaf(xf[1], wdc.y, d1);
        d1 = fmaf(xf[2], wdc.z, d1); d1 = fmaf(xf[3], wdc.w, d1);
        d1 = fmaf(xf[4], wdd.x, d1); d1 = fmaf(xf[5], wdd.y, d1);
        d1 = fmaf(xf[6], wdd.z, d1); d1 = fmaf(xf[7], wdd.w, d1);
    }
    for (int o = 32; o > 0; o >>= 1) {
        s0 += __shfl_down(s0, o); s1 += __shfl_down(s1, o);
        d0 += __shfl_down(d0, o); d1 += __shfl_down(d1, o);
    }
    if (lane == 0) {
        al_src[n * 2 + 0] = s0; al_src[n * 2 + 1] = s1;
        al_dst[n * 2 + 0] = d0; al_dst[n * 2 + 1] = d1;
        float l0 = s0 + d0; l0 = l0 > 0.f ? l0 : NEG * l0;
        float l1 = s1 + d1; l1 = l1 > 0.f ? l1 : NEG * l1;
        lself[n * 2 + 0] = l0; lself[n * 2 + 1] = l1;
        float e0 = expf(l0), e1 = expf(l1);
        for (int r = 0; r < NR; ++r) {
            s[(r * NN + n) * 2 + 0] = e0;
            s[(r * NN + n) * 2 + 1] = e1;
        }
        count[n] = 0;
    }
}

// pass 1: p = exp(leaky(al_src[s]+al_dst[d])), atomicAdd into s; optional count
__global__ void edge_pass1(EdgePtrs ep, const float* __restrict__ al_src,
                           const float* __restrict__ al_dst, float* __restrict__ s,
                           int* __restrict__ count, int docount) {
    int i = blockIdx.x * 256 + threadIdx.x;
    if (i >= NR * EE) return;
    int r = i / EE, ei = i - r * EE;
    const int* e = ep.e[r];
    int sN = e[ei];
    int d = e[EE + ei];
    float l0 = al_src[sN * 2 + 0] + al_dst[d * 2 + 0]; l0 = l0 > 0.f ? l0 : NEG * l0;
    float l1 = al_src[sN * 2 + 1] + al_dst[d * 2 + 1]; l1 = l1 > 0.f ? l1 : NEG * l1;
    atomicAdd(&s[(r * NN + d) * 2 + 0], expf(l0));
    atomicAdd(&s[(r * NN + d) * 2 + 1], expf(l1));
    if (docount) atomicAdd(&count[d], 1);
}

// pass 2: recompute p, alpha = p/(s+eps), scatter record to CSR slot
__global__ void edge_pass2(EdgePtrs ep, const float* __restrict__ al_src,
                           const float* __restrict__ al_dst, const float* __restrict__ s,
                           int* __restrict__ cursor, int4* __restrict__ recs) {
    int i = blockIdx.x * 256 + threadIdx.x;
    if (i >= NR * EE) return;
    int r = i / EE, ei = i - r * EE;
    const int* e = ep.e[r];
    int sN = e[ei];
    int d = e[EE + ei];
    float l0 = al_src[sN * 2 + 0] + al_dst[d * 2 + 0]; l0 = l0 > 0.f ? l0 : NEG * l0;
    float l1 = al_src[sN * 2 + 1] + al_dst[d * 2 + 1]; l1 = l1 > 0.f ? l1 : NEG * l1;
    float a0 = expf(l0) / (s[(r * NN + d) * 2 + 0] + 1e-16f);
    float a1 = expf(l1) / (s[(r * NN + d) * 2 + 1] + 1e-16f);
    int slot = atomicAdd(&cursor[d], 1);
    int4 rec;
    rec.x = sN;
    rec.y = __float_as_int(a0);
    rec.z = __float_as_int(a1);
    rec.w = 0;
    recs[slot] = rec;
}

// --- 3-stage parallel exclusive scan of count[NN] -> offs, cursor ---
__global__ void block_sum(const int* __restrict__ count, int* __restrict__ bsum) {
    int base = blockIdx.x * 1024;
    int tid = threadIdx.x;
    int s = 0;
    for (int i = tid; i < 1024; i += 256) {
        int idx = base + i;
        s += (idx < NN) ? count[idx] : 0;
    }
    for (int o = 32; o > 0; o >>= 1) s += __shfl_down(s, o);
    __shared__ int ws[4];
    if ((tid & 63) == 0) ws[tid >> 6] = s;
    __syncthreads();
    if (tid == 0) bsum[blockIdx.x] = ws[0] + ws[1] + ws[2] + ws[3];
}

__global__ void scan_small(const int* __restrict__ bsum, int* __restrict__ bbase,
                           int* __restrict__ offs) {
    if (threadIdx.x == 0) {
        int run = 0;
        for (int i = 0; i < NB; ++i) { bbase[i] = run; run += bsum[i]; }
        offs[NN] = run;
    }
}

__global__ void scan_blocks(const int* __restrict__ count, const int* __restrict__ bbase,
                            int* __restrict__ offs, int* __restrict__ cursor) {
    __shared__ int wsum[16];
    __shared__ int wbase[16];
    int tid = threadIdx.x;
    int lane = tid & 63;
    int wid = tid >> 6;
    int idx = blockIdx.x * 1024 + tid;
    int v = (idx < NN) ? count[idx] : 0;
    int xv = v;
    for (int d = 1; d < 64; d <<= 1) {
        int t = __shfl_up(xv, d);
        if (lane >= d) xv += t;
    }
    if (lane == 63) wsum[wid] = xv;
    __syncthreads();
    if (wid == 0 && lane < 16) {
        int wv = wsum[lane];
        int wx = wv;
        for (int d = 1; d < 16; d <<= 1) {
            int t = __shfl_up(wx, d);
            if (lane >= d) wx += t;
        }
        wbase[lane] = wx - wv;
    }
    __syncthreads();
    int excl = xv - v + wbase[wid] + bbase[blockIdx.x];
    if (idx < NN) { offs[idx] = excl; cursor[idx] = excl; }
}

__global__ void copy_cursor(const int* __restrict__ offs, int* __restrict__ cursor) {
    int i = blockIdx.x * 256 + threadIdx.x;
    if (i < NN) cursor[i] = offs[i];
}

// L1 aggregate: 2 blocks/node (one per head-half), 64 thr x 8 ch, 2-way ILP.
__global__ __launch_bounds__(64) void aggregate_l1(
    const unsigned short* __restrict__ xs, const int4* __restrict__ recs,
    const int* __restrict__ offs, const float* __restrict__ lself,
    const float* __restrict__ s, const float* __restrict__ bias,
    unsigned short* __restrict__ out) {
    int bid = blockIdx.x;
    int n = bid >> 1;
    int half = bid & 1;            // == head index (ch 0..511 -> h0, 512..1023 -> h1)
    int t = threadIdx.x;
    int c0 = half * 512 + t * 8;
    float els = expf(lself[n * 2 + half]);
    float coef = 0.f;
    for (int r = 0; r < NR; ++r)
        coef += els / (s[(r * NN + n) * 2 + half] + 1e-16f);
    float a0[8], a1[8], f[8];
    uint4 sv = *(const uint4*)&xs[(size_t)n * 1024 + c0];
    unpack8(sv, f);
#pragma unroll
    for (int j = 0; j < 8; ++j) {
        a0[j] = coef * f[j] + 6.f * bias[c0 + j];
        a1[j] = 0.f;
    }
    int beg = offs[n], end = offs[n + 1];
    int j = beg;
    for (; j + 1 < end; j += 2) {
        int4 r0 = recs[j], r1 = recs[j + 1];
        uint4 v0 = *(const uint4*)&xs[(size_t)r0.x * 1024 + c0];
        uint4 v1 = *(const uint4*)&xs[(size_t)r1.x * 1024 + c0];
        float al0 = half ? __int_as_float(r0.z) : __int_as_float(r0.y);
        float al1 = half ? __int_as_float(r1.z) : __int_as_float(r1.y);
        unpack8(v0, f);
#pragma unroll
        for (int q = 0; q < 8; ++q) a0[q] = fmaf(al0, f[q], a0[q]);
        unpack8(v1, f);
#pragma unroll
        for (int q = 0; q < 8; ++q) a1[q] = fmaf(al1, f[q], a1[q]);
    }
    if (j < end) {
        int4 r0 = recs[j];
        uint4 v0 = *(const uint4*)&xs[(size_t)r0.x * 1024 + c0];
        float al0 = half ? __int_as_float(r0.z) : __int_as_float(r0.y);
        unpack8(v0, f);
#pragma unroll
        for (int q = 0; q < 8; ++q) a0[q] = fmaf(al0, f[q], a0[q]);
    }
    uint4 o;
    o.x = pack2(fmaxf(a0[0] + a1[0], 0.f), fmaxf(a0[1] + a1[1], 0.f));
    o.y = pack2(fmaxf(a0[2] + a1[2], 0.f), fmaxf(a0[3] + a1[3], 0.f));
    o.z = pack2(fmaxf(a0[4] + a1[4], 0.f), fmaxf(a0[5] + a1[5], 0.f));
    o.w = pack2(fmaxf(a0[6] + a1[6], 0.f), fmaxf(a0[7] + a1[7], 0.f));
    *(uint4*)&out[(size_t)n * 1024 + c0] = o;
}

// L2 aggregate: 256 ch, bf16 in, fp32 out. 64 thr x 4 ch, 2-way ILP.
__global__ __launch_bounds__(64) void aggregate_l2(
    const unsigned short* __restrict__ xs, const int4* __restrict__ recs,
    const int* __restrict__ offs, const float* __restrict__ lself,
    const float* __restrict__ s, const float* __restrict__ bias,
    float* __restrict__ out) {
    int n = blockIdx.x;
    int t = threadIdx.x;
    int h = t >> 5;
    float els = expf(lself[n * 2 + h]);
    float coef = 0.f;
    for (int r = 0; r < NR; ++r)
        coef += els / (s[(r * NN + n) * 2 + h] + 1e-16f);
    float a0[4], a1[4];
    uint2 sv = *(const uint2*)&xs[(size_t)n * 256 + t * 4];
    a0[0] = coef * __uint_as_float(sv.x << 16)          + 6.f * bias[t * 4 + 0];
    a0[1] = coef * __uint_as_float(sv.x & 0xffff0000u)  + 6.f * bias[t * 4 + 1];
    a0[2] = coef * __uint_as_float(sv.y << 16)          + 6.f * bias[t * 4 + 2];
    a0[3] = coef * __uint_as_float(sv.y & 0xffff0000u)  + 6.f * bias[t * 4 + 3];
#pragma unroll
    for (int q = 0; q < 4; ++q) a1[q] = 0.f;
    int beg = offs[n], end = offs[n + 1];
    int j = beg;
    for (; j + 1 < end; j += 2) {
        int4 r0 = recs[j], r1 = recs[j + 1];
        uint2 v0 = *(const uint2*)&xs[(size_t)r0.x * 256 + t * 4];
        uint2 v1 = *(const uint2*)&xs[(size_t)r1.x * 256 + t * 4];
        float al0 = h ? __int_as_float(r0.z) : __int_as_float(r0.y);
        float al1 = h ? __int_as_float(r1.z) : __int_as_float(r1.y);
        a0[0] = fmaf(al0, __uint_as_float(v0.x << 16), a0[0]);
        a0[1] = fmaf(al0, __uint_as_float(v0.x & 0xffff0000u), a0[1]);
        a0[2] = fmaf(al0, __uint_as_float(v0.y << 16), a0[2]);
        a0[3] = fmaf(al0, __uint_as_float(v0.y & 0xffff0000u), a0[3]);
        a1[0] = fmaf(al1, __uint_as_float(v1.x << 16), a1[0]);
        a1[1] = fmaf(al1, __uint_as_float(v1.x & 0xffff0000u), a1[1]);
        a1[2] = fmaf(al1, __uint_as_float(v1.y << 16), a1[2]);
        a1[3] = fmaf(al1, __uint_as_float(v1.y & 0xffff0000u), a1[3]);
    }
    if (j < end) {
        int4 r0 = recs[j];
        uint2 v0 = *(const uint2*)&xs[(size_t)r0.x * 256 + t * 4];
        float al0 = h ? __int_as_float(r0.z) : __int_as_float(r0.y);
        a0[0] = fmaf(al0, __uint_as_float(v0.x << 16), a0[0]);
        a0[1] = fmaf(al0, __uint_as_float(v0.x & 0xffff0000u), a0[1]);
        a0[2] = fmaf(al0, __uint_as_float(v0.y << 16), a0[2]);
        a0[3] = fmaf(al0, __uint_as_float(v0.y & 0xffff0000u), a0[3]);
    }
    float4 o = make_float4(a0[0] + a1[0], a0[1] + a1[1], a0[2] + a1[2], a0[3] + a1[3]);
    *(float4*)&out[(size_t)n * 256 + t * 4] = o;
}

extern "C" void kernel_launch(void* const* d_in, const int* in_sizes, int n_in,
                              void* d_out, int out_size, void* d_ws, size_t ws_size,
                              hipStream_t stream) {
    const float* x = (const float*)d_in[0];
    EdgePtrs ep;
    for (int r = 0; r < NR; ++r) ep.e[r] = (const int*)d_in[1 + r];
    const float* W1s = (const float*)d_in[7];
    const float* W1d = (const float*)d_in[8];
    const float* a1s = (const float*)d_in[9];
    const float* a1d = (const float*)d_in[10];
    const float* b1  = (const float*)d_in[11];
    const float* W2s = (const float*)d_in[12];
    const float* W2d = (const float*)d_in[13];
    const float* a2s = (const float*)d_in[14];
    const float* a2d = (const float*)d_in[15];
    const float* b2  = (const float*)d_in[16];
    float* out = (float*)d_out;

    char* base = (char*)d_ws;
    size_t off = 0;
    auto take = [&](size_t nbytes) -> void* {
        void* p = base + off;
        off = (off + nbytes + 255) & ~(size_t)255;
        return p;
    };
    unsigned short* xb   = (unsigned short*)take((size_t)NN * 512 * 2);
    unsigned short* xs1b = (unsigned short*)take((size_t)NN * 1024 * 2);
    unsigned short* h1b  = (unsigned short*)take((size_t)NN * 1024 * 2);
    unsigned short* xs2b = xs1b;  // reuse (xs1 dead after L1 aggregate)
    unsigned short* Wb   = (unsigned short*)take((size_t)1024 * 512 * 2);
    float* alsrc = (float*)take((size_t)NN * HH * 4);
    float* aldst = (float*)take((size_t)NN * HH * 4);
    float* lself = (float*)take((size_t)NN * HH * 4);
    float* s     = (float*)take((size_t)NR * NN * HH * 4);
    int* count   = (int*)take((size_t)NN * 4);
    int* offs    = (int*)take((size_t)(NN + 1) * 4);
    int* cursor  = (int*)take((size_t)NN * 4);
    int4* recs   = (int4*)take((size_t)NR * EE * 16);
    float* wts   = (float*)take((size_t)HH * 1024 * 4);
    float* wtd   = (float*)take((size_t)HH * 1024 * 4);
    int* bsum    = (int*)take((size_t)NB * 4);
    int* bbase   = (int*)take((size_t)NB * 4);

    const int EB = (NR * EE + 255) / 256;

    // ---------------- Layer 1: K=512, C=512, Nout=1024 ----------------
    {
        const int K = 512, C = 512, Nout = 1024;
        f2b_kernel<<<(NN * 512 / 4 + 255) / 256, 256, 0, stream>>>(x, xb, NN * 512);
        f2b_kernel<<<(Nout * K / 4 + 255) / 256, 256, 0, stream>>>(W1s, Wb, Nout * K);
        fold_a_kernel<<<dim3(K / 64, HH), 256, 0, stream>>>(W1s, a1s, wts, C, K);
        fold_a_kernel<<<dim3(K / 64, HH), 256, 0, stream>>>(W1d, a1d, wtd, C, K);
        gemm_nt_mfma<<<dim3(Nout / 128, (NN + 127) / 128), 256, 0, stream>>>(xb, Wb, xs1b, NN, Nout, K);
        al_kernel_w<<<(NN + 3) / 4, 256, 0, stream>>>(xb, wts, wtd, K, alsrc, aldst, lself, s, count);
        edge_pass1<<<EB, 256, 0, stream>>>(ep, alsrc, aldst, s, count, 1);
        block_sum<<<NB, 256, 0, stream>>>(count, bsum);
        scan_small<<<1, 64, 0, stream>>>(bsum, bbase, offs);
        scan_blocks<<<NB, 1024, 0, stream>>>(count, bbase, offs, cursor);
        edge_pass2<<<EB, 256, 0, stream>>>(ep, alsrc, aldst, s, cursor, recs);
        aggregate_l1<<<NN * 2, 64, 0, stream>>>(xs1b, recs, offs, lself, s, b1, h1b);
    }
    // ---------------- Layer 2: K=1024, C=128, Nout=256 ----------------
    {
        const int K = 1024, C = 128, Nout = 256;
        f2b_kernel<<<(Nout * K / 4 + 255) / 256, 256, 0, stream>>>(W2s, Wb, Nout * K);
        fold_a_kernel<<<dim3(K / 64, HH), 256, 0, stream>>>(W2s, a2s, wts, C, K);
        fold_a_kernel<<<dim3(K / 64, HH), 256, 0, stream>>>(W2d, a2d, wtd, C, K);
        gemm_nt_mfma<<<dim3(Nout / 128, (NN + 127) / 128), 256, 0, stream>>>(h1b, Wb, xs2b, NN, Nout, K);
        al_kernel_w<<<(NN + 3) / 4, 256, 0, stream>>>(h1b, wts, wtd, K, alsrc, aldst, lself, s, count);
        edge_pass1<<<EB, 256, 0, stream>>>(ep, alsrc, aldst, s, count, 0);
        copy_cursor<<<(NN + 255) / 256, 256, 0, stream>>>(offs, cursor);
        edge_pass2<<<EB, 256, 0, stream>>>(ep, alsrc, aldst, s, cursor, recs);
        aggregate_l2<<<NN, 64, 0, stream>>>(xs2b, recs, offs, lself, s, b2, out);
    }
}